// Round 1
// baseline (1154.604 us; speedup 1.0000x reference)
//
#include <hip/hip_runtime.h>
#include <math.h>

#define N_NODES 50000
#define E_EDGES 400000

static constexpr float S_IN      = 0.17677669529663687f;   // 1/sqrt(32)
static constexpr float S_MID     = 0.125f;                 // 1/sqrt(64)
static constexpr float S_SE      = 0.08838834764831843f;   // 1/sqrt(128)
static constexpr float INV_NN    = 0.35355339059327373f;   // 1/sqrt(8)
static constexpr float INV_SQRT3 = 0.5773502691896258f;
static constexpr float FC1_S     = 0.25f;                  // 1/sqrt(16)
static constexpr float FC2_S     = 0.125f;                 // 1/sqrt(64)

// ---------------------------------------------------------------------------
// Kernel A: per-node precompute.
//   self = [x0@w_sc0, einsum(x1,w_sc1)] * a * S_IN   -> d_out node section
//   f    = [x0@w_lin1_0, einsum(x1,w_lin1_1)] * a * S_IN -> ws_f
// Block = 256 threads = 1 node; thread t computes one of 256 outputs.
// ---------------------------------------------------------------------------
__global__ __launch_bounds__(256) void node_pre_kernel(
    const float* __restrict__ node_input, const float* __restrict__ node_attr,
    const float* __restrict__ w_sc0, const float* __restrict__ w_sc1,
    const float* __restrict__ w_lin1_0, const float* __restrict__ w_lin1_1,
    float* __restrict__ out_self, float* __restrict__ ws_f)
{
    const int n = blockIdx.x;
    const int t = threadIdx.x;
    __shared__ __align__(16) float sx[128];
    if (t < 128) sx[t] = node_input[(size_t)n * 128 + t];
    __syncthreads();

    const float a = node_attr[n];
    const int half = t >> 7;   // 0: self, 1: f
    const int idx  = t & 127;

    float acc = 0.f;
    if (idx < 32) {
        const float* __restrict__ W = half ? w_lin1_0 : w_sc0;
        const int w = idx;
        #pragma unroll
        for (int u = 0; u < 32; ++u) acc += sx[u] * W[u * 32 + w];
    } else {
        const float* __restrict__ W = half ? w_lin1_1 : w_sc1;
        const int j = idx - 32;
        const int w = j / 3, m = j % 3;
        #pragma unroll
        for (int u = 0; u < 32; ++u) acc += sx[32 + u * 3 + m] * W[u * 32 + w];
    }
    acc *= a * S_IN;
    if (half == 0) out_self[(size_t)n * 128 + idx] = acc;
    else           ws_f[(size_t)n * 128 + idx]     = acc;
}

__device__ inline float wave_reduce_sum(float v) {
    #pragma unroll
    for (int off = 32; off >= 1; off >>= 1) v += __shfl_down(v, off, 64);
    return v;
}

// ---------------------------------------------------------------------------
// Kernel B: per-edge. Tile of 64 edges per block (256 threads = 4 waves).
// Phases: stage(W1,W2,es,meta) -> fc1->HT -> fc2(reg-blocked)->Wt -> message.
// LDS union: W2(8192)+HT(4352) region reused for Wt(8448) after fc2.
// ---------------------------------------------------------------------------
__global__ __launch_bounds__(256) void edge_kernel(
    const float* __restrict__ ws_f,
    const int* __restrict__ edge_src, const int* __restrict__ edge_dst,
    const float* __restrict__ edge_attr, const float* __restrict__ edge_scalars,
    const float* __restrict__ fc_w1, const float* __restrict__ fc_w2,
    const float* __restrict__ w_se0a, const float* __restrict__ w_se0b,
    const float* __restrict__ w_se1a, const float* __restrict__ w_se1b,
    float* __restrict__ nacc, float* __restrict__ edge_out)
{
    __shared__ __align__(16) float sW1[16 * 64];        // 4 KB
    __shared__ __align__(16) float sES[64 * 20];        // padded, 5 KB
    __shared__ int   sSRC[64];
    __shared__ int   sDST[64];
    __shared__ __align__(16) float sEA[64 * 4];
    __shared__ __align__(16) float sU[12544];           // union: W2+HT, then Wt

    const int t    = threadIdx.x;
    const int lane = t & 63;
    const int wv   = t >> 6;
    const int e0   = blockIdx.x * 64;

    // ---- stage ----
    {
        ((float4*)sW1)[t] = ((const float4*)fc_w1)[t];          // 1024 floats
        float4* sU4 = (float4*)sU;
        const float4* w24 = (const float4*)fc_w2;               // 8192 floats
        #pragma unroll
        for (int i = 0; i < 8; ++i) sU4[t + i * 256] = w24[t + i * 256];
        {   // edge_scalars tile: 64x16 contiguous -> padded 64x20
            float4 v = ((const float4*)(edge_scalars + (size_t)e0 * 16))[t];
            const int e = t >> 2, k = (t & 3) * 4;
            *((float4*)&sES[e * 20 + k]) = v;
        }
        if (t < 64)                 sSRC[t]      = edge_src[e0 + t];
        else if (t < 128)           sDST[t - 64] = edge_dst[e0 + (t - 64)];
        if (t < 64) {
            float4 v = ((const float4*)(edge_attr + (size_t)e0 * 4))[t];
            *((float4*)&sEA[t * 4]) = v;
        }
    }
    __syncthreads();

    float* sHT = sU + 8192;     // HT[j][e], row stride 68 (16B-aligned rows)

    // ---- fc1: h[e][j] = sin(0.25 * es[e] @ W1[:,j]) ----
    {
        const int e  = lane;            // within wave
        const int j0 = wv * 16;
        float acc[16];
        #pragma unroll
        for (int i = 0; i < 16; ++i) acc[i] = 0.f;
        #pragma unroll
        for (int k = 0; k < 16; ++k) {
            const float es = sES[e * 20 + k];
            #pragma unroll
            for (int i = 0; i < 16; ++i) acc[i] += es * sW1[k * 64 + j0 + i];
        }
        #pragma unroll
        for (int i = 0; i < 16; ++i)
            sHT[(j0 + i) * 68 + e] = sinf(acc[i] * FC1_S);
    }
    __syncthreads();

    // ---- fc2: w[e][c] = 0.125 * sum_j h[e][j] * W2[j][c]; 8 rows x 4 cols/thread
    float wacc[8][4];
    #pragma unroll
    for (int r = 0; r < 8; ++r)
        #pragma unroll
        for (int c = 0; c < 4; ++c) wacc[r][c] = 0.f;
    {
        const int c0 = (t & 31) * 4;
        const int r0 = (t >> 5) * 8;
        for (int k = 0; k < 64; ++k) {
            float4 wv4 = *(const float4*)&sU[k * 128 + c0];
            float4 ha  = *(const float4*)&sHT[k * 68 + r0];
            float4 hb  = *(const float4*)&sHT[k * 68 + r0 + 4];
            const float h[8]  = {ha.x, ha.y, ha.z, ha.w, hb.x, hb.y, hb.z, hb.w};
            const float wc[4] = {wv4.x, wv4.y, wv4.z, wv4.w};
            #pragma unroll
            for (int r = 0; r < 8; ++r)
                #pragma unroll
                for (int c = 0; c < 4; ++c) wacc[r][c] += h[r] * wc[c];
        }
    }
    __syncthreads();            // all W2/HT reads done; safe to overwrite

    float* sWt = sU;            // Wt[e][c], row stride 132 (16B-aligned rows)
    {
        const int c0 = (t & 31) * 4;
        const int r0 = (t >> 5) * 8;
        #pragma unroll
        for (int r = 0; r < 8; ++r) {
            float4 v;
            v.x = wacc[r][0] * FC2_S; v.y = wacc[r][1] * FC2_S;
            v.z = wacc[r][2] * FC2_S; v.w = wacc[r][3] * FC2_S;
            *(float4*)&sWt[(r0 + r) * 132 + c0] = v;
        }
    }
    __syncthreads();

    // ---- message phase: each wave handles 16 edges, batched 4 for MLP ----
    const float se0a = w_se0a[lane], se0b = w_se0b[lane];
    const float se1a = w_se1a[lane], se1b = w_se1b[lane];
    const bool hi = lane >= 32;
    const int  u  = lane - 32;
    const int idxA = hi ? (32 + 3 * u) : lane;   // g0[l] | g1[u][0]
    const int idxB = hi ? (33 + 3 * u) : lane;   //        | g1[u][1]
    const int idxC = hi ? (34 + 3 * u) : lane;   //        | g1[u][2]
    const int col1 = hi ? (96 + u) : lane;        // wD[u] | wA[l]
    const int col2 = hi ? (64 + u) : (32 + lane); // wC[u] | wB[l]

    for (int b = 0; b < 4; ++b) {
        float ga[4], gb[4], gc[4];
        int eloc[4];
        #pragma unroll
        for (int i = 0; i < 4; ++i) {
            const int el = wv * 16 + b * 4 + i;
            eloc[i] = el;
            const float* fr = ws_f + (size_t)sSRC[el] * 128;
            ga[i] = fr[idxA]; gb[i] = fr[idxB]; gc[i] = fr[idxC];
        }
        #pragma unroll
        for (int i = 0; i < 4; ++i) {
            const int el  = eloc[i];
            const int dst = sDST[el];
            const float ea0 = sEA[el * 4 + 0];
            const float e1x = sEA[el * 4 + 1];
            const float e1y = sEA[el * 4 + 2];
            const float e1z = sEA[el * 4 + 3];
            const float w1v = sWt[el * 132 + col1];
            const float w2v = sWt[el * 132 + col2];

            float mid0, m1x, m1y, m1z;
            if (!hi) {                       // lanes 0..31: mA, mB
                mid0 = w1v * ga[i] * ea0;
                const float wbg = w2v * ga[i];
                m1x = wbg * e1x; m1y = wbg * e1y; m1z = wbg * e1z;
            } else {                         // lanes 32..63: mD, mC
                const float dot = ga[i] * e1x + gb[i] * e1y + gc[i] * e1z;
                mid0 = w1v * dot * INV_SQRT3;
                const float wce = w2v * ea0;
                m1x = wce * ga[i]; m1y = wce * gb[i]; m1z = wce * gc[i];
            }

            float* np_ = nacc + (size_t)dst * 256;
            atomicAdd(np_ + lane, mid0);
            atomicAdd(np_ + 64 + lane * 3 + 0, m1x);
            atomicAdd(np_ + 64 + lane * 3 + 1, m1y);
            atomicAdd(np_ + 64 + lane * 3 + 2, m1z);

            // edge self-interaction reductions
            const float dotm = m1x * e1x + m1y * e1y + m1z * e1z;
            float r0  = wave_reduce_sum(mid0 * se0a);
            float r1  = wave_reduce_sum(dotm * se0b);
            float r2  = wave_reduce_sum(mid0 * se1a);
            float r3x = wave_reduce_sum(m1x * se1b);
            float r3y = wave_reduce_sum(m1y * se1b);
            float r3z = wave_reduce_sum(m1z * se1b);

            if (lane == 0) {
                const float se0 = (r0 * ea0 + r1 * INV_SQRT3) * S_SE;
                float4 o;
                o.x = ea0 + se0 * INV_NN;
                o.y = e1x + (r2 * e1x + r3x * ea0) * S_SE * INV_NN;
                o.z = e1y + (r2 * e1y + r3y * ea0) * S_SE * INV_NN;
                o.w = e1z + (r2 * e1z + r3z * ea0) * S_SE * INV_NN;
                *(float4*)&edge_out[(size_t)(e0 + el) * 4] = o;
            }
        }
    }
}

// ---------------------------------------------------------------------------
// Kernel C: per-node post. out = self + alpha * (n @ w_lin2) with scales.
// Block = 128 threads = 1 node; thread t computes output element t.
// ---------------------------------------------------------------------------
__global__ __launch_bounds__(128) void node_post_kernel(
    const float* __restrict__ nacc, const float* __restrict__ node_attr,
    const float* __restrict__ w_lin2_0, const float* __restrict__ w_lin2_1,
    const float* __restrict__ w_alpha, float* __restrict__ out)
{
    const int n = blockIdx.x, t = threadIdx.x;
    __shared__ __align__(16) float sn[256];
    sn[t]       = nacc[(size_t)n * 256 + t];
    sn[t + 128] = nacc[(size_t)n * 256 + 128 + t];
    __syncthreads();

    const float a = node_attr[n];
    float accM = 0.f, accA = 0.f;
    if (t < 32) {
        #pragma unroll
        for (int u = 0; u < 64; ++u) {
            accM += sn[u] * w_lin2_0[u * 32 + t];
            accA += sn[u] * w_alpha[u];
        }
    } else {
        const int j = t - 32;
        const int w = j / 3, m = j % 3;
        #pragma unroll
        for (int u = 0; u < 64; ++u) {
            accM += sn[64 + u * 3 + m] * w_lin2_1[u * 32 + w];
            accA += sn[u] * w_alpha[u];
        }
    }
    const float s     = a * S_MID * INV_NN;   // fold segment-sum inv_nn here
    const float alpha = accA * s;
    const float conv  = accM * s;
    const float self  = out[(size_t)n * 128 + t];
    out[(size_t)n * 128 + t] = self + alpha * conv;
}

extern "C" void kernel_launch(void* const* d_in, const int* in_sizes, int n_in,
                              void* d_out, int out_size, void* d_ws, size_t ws_size,
                              hipStream_t stream)
{
    const float* node_input   = (const float*)d_in[0];
    const float* node_attr    = (const float*)d_in[1];
    const int*   edge_src     = (const int*)d_in[2];
    const int*   edge_dst     = (const int*)d_in[3];
    const float* edge_attr    = (const float*)d_in[4];
    const float* edge_scalars = (const float*)d_in[5];
    const float* w_sc0        = (const float*)d_in[6];
    const float* w_sc1        = (const float*)d_in[7];
    const float* w_lin1_0     = (const float*)d_in[8];
    const float* w_lin1_1     = (const float*)d_in[9];
    const float* fc_w1        = (const float*)d_in[10];
    const float* fc_w2        = (const float*)d_in[11];
    const float* w_lin2_0     = (const float*)d_in[12];
    const float* w_lin2_1     = (const float*)d_in[13];
    const float* w_alpha      = (const float*)d_in[14];
    const float* w_se0a       = (const float*)d_in[15];
    const float* w_se0b       = (const float*)d_in[16];
    const float* w_se1a       = (const float*)d_in[17];
    const float* w_se1b       = (const float*)d_in[18];

    float* out      = (float*)d_out;
    float* edge_out = out + (size_t)N_NODES * 128;

    float* ws_f = (float*)d_ws;                       // N*128 floats
    float* nacc = ws_f + (size_t)N_NODES * 128;       // N*256 floats

    hipMemsetAsync(nacc, 0, (size_t)N_NODES * 256 * sizeof(float), stream);

    node_pre_kernel<<<N_NODES, 256, 0, stream>>>(
        node_input, node_attr, w_sc0, w_sc1, w_lin1_0, w_lin1_1, out, ws_f);

    edge_kernel<<<E_EDGES / 64, 256, 0, stream>>>(
        ws_f, edge_src, edge_dst, edge_attr, edge_scalars, fc_w1, fc_w2,
        w_se0a, w_se0b, w_se1a, w_se1b, nacc, edge_out);

    node_post_kernel<<<N_NODES, 128, 0, stream>>>(
        nacc, node_attr, w_lin2_0, w_lin2_1, w_alpha, out);
}

// Round 2
// 634.757 us; speedup vs baseline: 1.8190x; 1.8190x over previous
//
#include <hip/hip_runtime.h>
#include <math.h>

#define N_NODES 50000
#define E_EDGES 400000

typedef _Float16 half4 __attribute__((ext_vector_type(4)));

static constexpr float S_IN      = 0.17677669529663687f;   // 1/sqrt(32)
static constexpr float S_MID     = 0.125f;                 // 1/sqrt(64)
static constexpr float S_SE      = 0.08838834764831843f;   // 1/sqrt(128)
static constexpr float INV_NN    = 0.35355339059327373f;   // 1/sqrt(8)
static constexpr float INV_SQRT3 = 0.5773502691896258f;
static constexpr float FC1_S     = 0.25f;                  // 1/sqrt(16)
static constexpr float FC2_S     = 0.125f;                 // 1/sqrt(64)

// ---------------------------------------------------------------------------
// Kernel A: per-node precompute (unchanged from round 1 — not the bottleneck).
// ---------------------------------------------------------------------------
__global__ __launch_bounds__(256) void node_pre_kernel(
    const float* __restrict__ node_input, const float* __restrict__ node_attr,
    const float* __restrict__ w_sc0, const float* __restrict__ w_sc1,
    const float* __restrict__ w_lin1_0, const float* __restrict__ w_lin1_1,
    float* __restrict__ out_self, float* __restrict__ ws_f)
{
    const int n = blockIdx.x;
    const int t = threadIdx.x;
    __shared__ __align__(16) float sx[128];
    if (t < 128) sx[t] = node_input[(size_t)n * 128 + t];
    __syncthreads();

    const float a = node_attr[n];
    const int half = t >> 7;   // 0: self, 1: f
    const int idx  = t & 127;

    float acc = 0.f;
    if (idx < 32) {
        const float* __restrict__ W = half ? w_lin1_0 : w_sc0;
        const int w = idx;
        #pragma unroll
        for (int u = 0; u < 32; ++u) acc += sx[u] * W[u * 32 + w];
    } else {
        const float* __restrict__ W = half ? w_lin1_1 : w_sc1;
        const int j = idx - 32;
        const int w = j / 3, m = j % 3;
        #pragma unroll
        for (int u = 0; u < 32; ++u) acc += sx[32 + u * 3 + m] * W[u * 32 + w];
    }
    acc *= a * S_IN;
    if (half == 0) out_self[(size_t)n * 128 + idx] = acc;
    else           ws_f[(size_t)n * 128 + idx]     = acc;
}

// ---------------------------------------------------------------------------
// Counting sort of edges by dst: hist -> scan -> scatter
// ---------------------------------------------------------------------------
__global__ __launch_bounds__(256) void hist_kernel(
    const int* __restrict__ edge_dst, int* __restrict__ counts)
{
    const int e = blockIdx.x * 256 + threadIdx.x;
    if (e < E_EDGES) atomicAdd(&counts[edge_dst[e]], 1);
}

__global__ __launch_bounds__(1024) void scan_kernel(
    const int* __restrict__ counts, int* __restrict__ cursor)
{
    __shared__ int part[1024];
    const int t = threadIdx.x;
    const int CH = 49;                 // 1024*49 = 50176 >= 50000
    int loc[49];
    int s = 0;
    #pragma unroll
    for (int i = 0; i < CH; ++i) {
        const int idx = t * CH + i;
        const int c = (idx < N_NODES) ? counts[idx] : 0;
        loc[i] = c; s += c;
    }
    part[t] = s;
    __syncthreads();
    // Hillis-Steele inclusive scan over 1024 partials
    for (int off = 1; off < 1024; off <<= 1) {
        int v = (t >= off) ? part[t - off] : 0;
        __syncthreads();
        part[t] += v;
        __syncthreads();
    }
    int pre = (t == 0) ? 0 : part[t - 1];
    #pragma unroll
    for (int i = 0; i < CH; ++i) {
        const int idx = t * CH + i;
        if (idx < N_NODES) cursor[idx] = pre;
        pre += loc[i];
    }
}

__global__ __launch_bounds__(256) void scatter_kernel(
    const int* __restrict__ edge_dst, int* __restrict__ cursor,
    int* __restrict__ sorted_eid)
{
    const int e = blockIdx.x * 256 + threadIdx.x;
    if (e < E_EDGES) {
        const int p = atomicAdd(&cursor[edge_dst[e]], 1);
        sorted_eid[p] = e;
    }
}

__device__ inline float wave_reduce_sum(float v) {
    #pragma unroll
    for (int off = 32; off >= 1; off >>= 1) v += __shfl_down(v, off, 64);
    return v;
}

// ---------------------------------------------------------------------------
// Kernel B: per-edge, walking edges in dst-sorted order. 64 edges / block.
// LDS: W1(4K) + ES(5K) + W2 fp16(16K) + union{HT fp32 17K | Wt fp16 16K}
//      + EA(1K) + SRC/DST/EID(0.75K)  ~= 44 KB  -> 3 blocks/CU.
// Node accumulation: per-wave register accumulators per dst segment, flushed
// with 4 atomics/lane on segment change (~19M atomics vs 102M in round 1).
// ---------------------------------------------------------------------------
__global__ __launch_bounds__(256, 3) void edge_kernel(
    const float* __restrict__ ws_f,
    const int* __restrict__ edge_src, const int* __restrict__ edge_dst,
    const float* __restrict__ edge_attr, const float* __restrict__ edge_scalars,
    const float* __restrict__ fc_w1, const float* __restrict__ fc_w2,
    const float* __restrict__ w_se0a, const float* __restrict__ w_se0b,
    const float* __restrict__ w_se1a, const float* __restrict__ w_se1b,
    const int* __restrict__ sorted_eid,
    float* __restrict__ nacc, float* __restrict__ edge_out)
{
    __shared__ __align__(16) float     sW1[16 * 64];    // 4 KB
    __shared__ __align__(16) float     sES[64 * 20];    // 5 KB (padded)
    __shared__ __align__(16) _Float16  sW2h[64 * 128];  // 16 KB
    __shared__ __align__(16) float     sUN[4352];       // 17 KB: HT | Wt(fp16)
    __shared__ __align__(16) float     sEA[64 * 4];
    __shared__ int sSRC[64];
    __shared__ int sDST[64];
    __shared__ int sEID[64];

    const int t    = threadIdx.x;
    const int lane = t & 63;
    const int wv   = t >> 6;
    const int e0   = blockIdx.x * 64;

    // ---- stage ----
    {
        ((float4*)sW1)[t] = ((const float4*)fc_w1)[t];          // 1024 floats
        const float4* w24 = (const float4*)fc_w2;               // 8192 floats
        #pragma unroll
        for (int i = 0; i < 8; ++i) {
            float4 w = w24[t + i * 256];
            half4 h; h[0] = (_Float16)w.x; h[1] = (_Float16)w.y;
                     h[2] = (_Float16)w.z; h[3] = (_Float16)w.w;
            ((half4*)sW2h)[t + i * 256] = h;
        }
        {   // edge_scalars gather: 4 threads per edge, 64B rows
            const int e  = t >> 2, k4 = t & 3;
            const int eid = sorted_eid[e0 + e];
            float4 v = ((const float4*)edge_scalars)[(size_t)eid * 4 + k4];
            *((float4*)&sES[e * 20 + k4 * 4]) = v;
        }
        if (t < 64) {
            const int eid = sorted_eid[e0 + t];
            float4 v = ((const float4*)edge_attr)[eid];
            *((float4*)&sEA[t * 4]) = v;
        } else if (t < 128) {
            sSRC[t - 64] = edge_src[sorted_eid[e0 + (t - 64)]];
        } else if (t < 192) {
            sDST[t - 128] = edge_dst[sorted_eid[e0 + (t - 128)]];
        } else {
            sEID[t - 192] = sorted_eid[e0 + (t - 192)];
        }
    }
    __syncthreads();

    float* sHT = sUN;                     // HT[j][e], row stride 68

    // ---- fc1: h[e][j] = sin(0.25 * es[e] @ W1[:,j]) ----
    {
        const int e  = lane;
        const int j0 = wv * 16;
        float acc[16];
        #pragma unroll
        for (int i = 0; i < 16; ++i) acc[i] = 0.f;
        #pragma unroll
        for (int k = 0; k < 16; ++k) {
            const float es = sES[e * 20 + k];
            #pragma unroll
            for (int i = 0; i < 16; ++i) acc[i] += es * sW1[k * 64 + j0 + i];
        }
        #pragma unroll
        for (int i = 0; i < 16; ++i)
            sHT[(j0 + i) * 68 + e] = __sinf(acc[i] * FC1_S);
    }
    __syncthreads();

    // ---- fc2: w[e][c] = 0.125 * sum_j h[j][e] * W2[j][c]; 8 rows x 4 cols ----
    float wacc[8][4];
    #pragma unroll
    for (int r = 0; r < 8; ++r)
        #pragma unroll
        for (int c = 0; c < 4; ++c) wacc[r][c] = 0.f;
    {
        const int c0 = (t & 31) * 4;
        const int r0 = (t >> 5) * 8;
        for (int k = 0; k < 64; ++k) {
            half4 wh  = *(const half4*)&sW2h[k * 128 + c0];
            float4 ha = *(const float4*)&sHT[k * 68 + r0];
            float4 hb = *(const float4*)&sHT[k * 68 + r0 + 4];
            const float h[8]  = {ha.x, ha.y, ha.z, ha.w, hb.x, hb.y, hb.z, hb.w};
            const float wc[4] = {(float)wh[0], (float)wh[1], (float)wh[2], (float)wh[3]};
            #pragma unroll
            for (int r = 0; r < 8; ++r)
                #pragma unroll
                for (int c = 0; c < 4; ++c) wacc[r][c] += h[r] * wc[c];
        }
    }
    __syncthreads();            // HT reads done; safe to overwrite union

    _Float16* sWtH = (_Float16*)sUN;      // Wt[e][c] fp16, row stride 128
    {
        const int c0 = (t & 31) * 4;
        const int r0 = (t >> 5) * 8;
        #pragma unroll
        for (int r = 0; r < 8; ++r) {
            half4 v;
            v[0] = (_Float16)(wacc[r][0] * FC2_S);
            v[1] = (_Float16)(wacc[r][1] * FC2_S);
            v[2] = (_Float16)(wacc[r][2] * FC2_S);
            v[3] = (_Float16)(wacc[r][3] * FC2_S);
            *(half4*)&sWtH[(r0 + r) * 128 + c0] = v;
        }
    }
    __syncthreads();

    // ---- message phase: 16 sorted edges per wave, register-accumulated ----
    const float se0a = w_se0a[lane], se0b = w_se0b[lane];
    const float se1a = w_se1a[lane], se1b = w_se1b[lane];
    const bool hi = lane >= 32;
    const int  u  = lane - 32;
    const int idxA = hi ? (32 + 3 * u) : lane;
    const int idxB = hi ? (33 + 3 * u) : lane;
    const int idxC = hi ? (34 + 3 * u) : lane;
    const int col1 = hi ? (96 + u) : lane;        // wD[u] | wA[l]
    const int col2 = hi ? (64 + u) : (32 + lane); // wC[u] | wB[l]

    int   cur = -1;
    float am0 = 0.f, axx = 0.f, ayy = 0.f, azz = 0.f;

    for (int b = 0; b < 4; ++b) {
        float ga[4], gb[4], gc[4];
        #pragma unroll
        for (int i = 0; i < 4; ++i) {
            const int el = wv * 16 + b * 4 + i;
            const float* fr = ws_f + (size_t)sSRC[el] * 128;
            ga[i] = fr[idxA]; gb[i] = fr[idxB]; gc[i] = fr[idxC];
        }
        #pragma unroll
        for (int i = 0; i < 4; ++i) {
            const int el  = wv * 16 + b * 4 + i;
            const int dst = sDST[el];
            const float ea0 = sEA[el * 4 + 0];
            const float e1x = sEA[el * 4 + 1];
            const float e1y = sEA[el * 4 + 2];
            const float e1z = sEA[el * 4 + 3];
            const float w1v = (float)sWtH[el * 128 + col1];
            const float w2v = (float)sWtH[el * 128 + col2];

            float mid0, m1x, m1y, m1z;
            if (!hi) {                       // lanes 0..31: mA, mB
                mid0 = w1v * ga[i] * ea0;
                const float wbg = w2v * ga[i];
                m1x = wbg * e1x; m1y = wbg * e1y; m1z = wbg * e1z;
            } else {                         // lanes 32..63: mD, mC
                const float dot = ga[i] * e1x + gb[i] * e1y + gc[i] * e1z;
                mid0 = w1v * dot * INV_SQRT3;
                const float wce = w2v * ea0;
                m1x = wce * ga[i]; m1y = wce * gb[i]; m1z = wce * gc[i];
            }

            // segment-change flush (dst is wave-uniform)
            if (dst != cur) {
                if (cur >= 0) {
                    float* np_ = nacc + (size_t)cur * 256;
                    atomicAdd(np_ + lane, am0);
                    atomicAdd(np_ + 64 + lane * 3 + 0, axx);
                    atomicAdd(np_ + 64 + lane * 3 + 1, ayy);
                    atomicAdd(np_ + 64 + lane * 3 + 2, azz);
                }
                cur = dst; am0 = axx = ayy = azz = 0.f;
            }
            am0 += mid0; axx += m1x; ayy += m1y; azz += m1z;

            // edge self-interaction reductions
            const float dotm = m1x * e1x + m1y * e1y + m1z * e1z;
            float r0  = wave_reduce_sum(mid0 * se0a);
            float r1  = wave_reduce_sum(dotm * se0b);
            float r2  = wave_reduce_sum(mid0 * se1a);
            float r3x = wave_reduce_sum(m1x * se1b);
            float r3y = wave_reduce_sum(m1y * se1b);
            float r3z = wave_reduce_sum(m1z * se1b);

            if (lane == 0) {
                const float se0 = (r0 * ea0 + r1 * INV_SQRT3) * S_SE;
                float4 o;
                o.x = ea0 + se0 * INV_NN;
                o.y = e1x + (r2 * e1x + r3x * ea0) * S_SE * INV_NN;
                o.z = e1y + (r2 * e1y + r3y * ea0) * S_SE * INV_NN;
                o.w = e1z + (r2 * e1z + r3z * ea0) * S_SE * INV_NN;
                *(float4*)&edge_out[(size_t)sEID[el] * 4] = o;
            }
        }
    }
    if (cur >= 0) {
        float* np_ = nacc + (size_t)cur * 256;
        atomicAdd(np_ + lane, am0);
        atomicAdd(np_ + 64 + lane * 3 + 0, axx);
        atomicAdd(np_ + 64 + lane * 3 + 1, ayy);
        atomicAdd(np_ + 64 + lane * 3 + 2, azz);
    }
}

// ---------------------------------------------------------------------------
// Kernel C: per-node post (unchanged).
// ---------------------------------------------------------------------------
__global__ __launch_bounds__(128) void node_post_kernel(
    const float* __restrict__ nacc, const float* __restrict__ node_attr,
    const float* __restrict__ w_lin2_0, const float* __restrict__ w_lin2_1,
    const float* __restrict__ w_alpha, float* __restrict__ out)
{
    const int n = blockIdx.x, t = threadIdx.x;
    __shared__ __align__(16) float sn[256];
    sn[t]       = nacc[(size_t)n * 256 + t];
    sn[t + 128] = nacc[(size_t)n * 256 + 128 + t];
    __syncthreads();

    const float a = node_attr[n];
    float accM = 0.f, accA = 0.f;
    if (t < 32) {
        #pragma unroll
        for (int u = 0; u < 64; ++u) {
            accM += sn[u] * w_lin2_0[u * 32 + t];
            accA += sn[u] * w_alpha[u];
        }
    } else {
        const int j = t - 32;
        const int w = j / 3, m = j % 3;
        #pragma unroll
        for (int u = 0; u < 64; ++u) {
            accM += sn[64 + u * 3 + m] * w_lin2_1[u * 32 + w];
            accA += sn[u] * w_alpha[u];
        }
    }
    const float s     = a * S_MID * INV_NN;
    const float alpha = accA * s;
    const float conv  = accM * s;
    const float self  = out[(size_t)n * 128 + t];
    out[(size_t)n * 128 + t] = self + alpha * conv;
}

extern "C" void kernel_launch(void* const* d_in, const int* in_sizes, int n_in,
                              void* d_out, int out_size, void* d_ws, size_t ws_size,
                              hipStream_t stream)
{
    const float* node_input   = (const float*)d_in[0];
    const float* node_attr    = (const float*)d_in[1];
    const int*   edge_src     = (const int*)d_in[2];
    const int*   edge_dst     = (const int*)d_in[3];
    const float* edge_attr    = (const float*)d_in[4];
    const float* edge_scalars = (const float*)d_in[5];
    const float* w_sc0        = (const float*)d_in[6];
    const float* w_sc1        = (const float*)d_in[7];
    const float* w_lin1_0     = (const float*)d_in[8];
    const float* w_lin1_1     = (const float*)d_in[9];
    const float* fc_w1        = (const float*)d_in[10];
    const float* fc_w2        = (const float*)d_in[11];
    const float* w_lin2_0     = (const float*)d_in[12];
    const float* w_lin2_1     = (const float*)d_in[13];
    const float* w_alpha      = (const float*)d_in[14];
    const float* w_se0a       = (const float*)d_in[15];
    const float* w_se0b       = (const float*)d_in[16];
    const float* w_se1a       = (const float*)d_in[17];
    const float* w_se1b       = (const float*)d_in[18];

    float* out      = (float*)d_out;
    float* edge_out = out + (size_t)N_NODES * 128;

    float* ws_f  = (float*)d_ws;                        // N*128 f
    float* nacc  = ws_f + (size_t)N_NODES * 128;        // N*256 f
    int*   counts = (int*)(nacc + (size_t)N_NODES * 256);  // N
    int*   cursor = counts + N_NODES;                      // N
    int*   sid    = cursor + N_NODES;                      // E

    // zero nacc + counts in one shot (contiguous)
    hipMemsetAsync(nacc, 0,
        ((size_t)N_NODES * 256 + N_NODES) * sizeof(float), stream);

    node_pre_kernel<<<N_NODES, 256, 0, stream>>>(
        node_input, node_attr, w_sc0, w_sc1, w_lin1_0, w_lin1_1, out, ws_f);

    hist_kernel<<<(E_EDGES + 255) / 256, 256, 0, stream>>>(edge_dst, counts);
    scan_kernel<<<1, 1024, 0, stream>>>(counts, cursor);
    scatter_kernel<<<(E_EDGES + 255) / 256, 256, 0, stream>>>(edge_dst, cursor, sid);

    edge_kernel<<<E_EDGES / 64, 256, 0, stream>>>(
        ws_f, edge_src, edge_dst, edge_attr, edge_scalars, fc_w1, fc_w2,
        w_se0a, w_se0b, w_se1a, w_se1b, sid, nacc, edge_out);

    node_post_kernel<<<N_NODES, 128, 0, stream>>>(
        nacc, node_attr, w_lin2_0, w_lin2_1, w_alpha, out);
}

// Round 3
// 429.833 us; speedup vs baseline: 2.6862x; 1.4768x over previous
//
#include <hip/hip_runtime.h>
#include <math.h>

#define N_NODES 50000
#define E_EDGES 400000

typedef _Float16 f16x2 __attribute__((ext_vector_type(2)));
typedef _Float16 f16x4 __attribute__((ext_vector_type(4)));
typedef _Float16 f16x8 __attribute__((ext_vector_type(8)));

static constexpr float S_IN      = 0.17677669529663687f;   // 1/sqrt(32)
static constexpr float S_MID     = 0.125f;                 // 1/sqrt(64)
static constexpr float S_SE      = 0.08838834764831843f;   // 1/sqrt(128)
static constexpr float INV_NN    = 0.35355339059327373f;   // 1/sqrt(8)
static constexpr float INV_SQRT3 = 0.5773502691896258f;
static constexpr float FC1_S     = 0.25f;                  // 1/sqrt(16)
static constexpr float FC2_S     = 0.125f;                 // 1/sqrt(64)

// f16x2 dot with fp32 accumulate (v_dot2_f32_f16)
__device__ inline float dot2(f16x2 a, f16x2 b, float c) {
#if __has_builtin(__builtin_amdgcn_fdot2)
    return __builtin_amdgcn_fdot2(a, b, c, false);
#else
    return c + (float)a[0] * (float)b[0] + (float)a[1] * (float)b[1];
#endif
}

// 64-lane sum via DPP (VALU pipe, no DS): row_shr 1/2/4/8, bcast15, bcast31.
__device__ inline float wave_reduce_dpp(float v) {
    int x;
    x = __builtin_amdgcn_update_dpp(0, __float_as_int(v), 0x111, 0xf, 0xf, true); v += __int_as_float(x);
    x = __builtin_amdgcn_update_dpp(0, __float_as_int(v), 0x112, 0xf, 0xf, true); v += __int_as_float(x);
    x = __builtin_amdgcn_update_dpp(0, __float_as_int(v), 0x114, 0xf, 0xf, true); v += __int_as_float(x);
    x = __builtin_amdgcn_update_dpp(0, __float_as_int(v), 0x118, 0xf, 0xf, true); v += __int_as_float(x);
    x = __builtin_amdgcn_update_dpp(0, __float_as_int(v), 0x142, 0xa, 0xf, true); v += __int_as_float(x);
    x = __builtin_amdgcn_update_dpp(0, __float_as_int(v), 0x143, 0xc, 0xf, true); v += __int_as_float(x);
    return __int_as_float(__builtin_amdgcn_readlane(__float_as_int(v), 63));
}

// ---------------------------------------------------------------------------
// Kernel A: per-node precompute; 8 nodes/block, weight column in registers.
// ---------------------------------------------------------------------------
__global__ __launch_bounds__(256) void node_pre_kernel(
    const float* __restrict__ node_input, const float* __restrict__ node_attr,
    const float* __restrict__ w_sc0, const float* __restrict__ w_sc1,
    const float* __restrict__ w_lin1_0, const float* __restrict__ w_lin1_1,
    float* __restrict__ out_self, float* __restrict__ ws_f)
{
    const int n0 = blockIdx.x * 8;
    const int t  = threadIdx.x;
    __shared__ __align__(16) float sx[8 * 128];
    __shared__ float sa[8];
    ((float4*)sx)[t] = ((const float4*)(node_input + (size_t)n0 * 128))[t];
    if (t < 8) sa[t] = node_attr[n0 + t];
    __syncthreads();

    const int half = t >> 7;
    const int idx  = t & 127;
    float wcol[32];
    int m = 0;
    if (idx < 32) {
        const float* __restrict__ W = half ? w_lin1_0 : w_sc0;
        #pragma unroll
        for (int u = 0; u < 32; ++u) wcol[u] = W[u * 32 + idx];
    } else {
        const float* __restrict__ W = half ? w_lin1_1 : w_sc1;
        const int j = idx - 32;
        const int w = j / 3; m = j % 3;
        #pragma unroll
        for (int u = 0; u < 32; ++u) wcol[u] = W[u * 32 + w];
    }
    float* __restrict__ dstp = half ? ws_f : out_self;
    #pragma unroll
    for (int k = 0; k < 8; ++k) {
        const float* x = sx + k * 128;
        float acc = 0.f;
        if (idx < 32) {
            #pragma unroll
            for (int u = 0; u < 32; ++u) acc += x[u] * wcol[u];
        } else {
            #pragma unroll
            for (int u = 0; u < 32; ++u) acc += x[32 + u * 3 + m] * wcol[u];
        }
        dstp[(size_t)(n0 + k) * 128 + idx] = acc * sa[k] * S_IN;
    }
}

// ---------------------------------------------------------------------------
// Counting sort by dst: hist -> block scan -> bsum scan -> fixup -> scatter
// ---------------------------------------------------------------------------
__global__ __launch_bounds__(256) void hist_kernel(
    const int* __restrict__ edge_dst, int* __restrict__ counts)
{
    const int e = blockIdx.x * 256 + threadIdx.x;
    if (e < E_EDGES) atomicAdd(&counts[edge_dst[e]], 1);
}

__global__ __launch_bounds__(1024) void scan_block_kernel(
    const int* __restrict__ counts, int* __restrict__ cursor, int* __restrict__ bsum)
{
    __shared__ int sd[1024];
    const int t   = threadIdx.x;
    const int idx = blockIdx.x * 1024 + t;
    const int c   = (idx < N_NODES) ? counts[idx] : 0;
    sd[t] = c;
    __syncthreads();
    for (int off = 1; off < 1024; off <<= 1) {
        const int v = (t >= off) ? sd[t - off] : 0;
        __syncthreads();
        sd[t] += v;
        __syncthreads();
    }
    if (idx < N_NODES) cursor[idx] = sd[t] - c;   // block-local exclusive
    if (t == 1023) bsum[blockIdx.x] = sd[1023];
}

__global__ void scan_bsum_kernel(const int* __restrict__ bsum, int* __restrict__ boff) {
    if (threadIdx.x == 0) {
        int run = 0;
        for (int b = 0; b < 49; ++b) { boff[b] = run; run += bsum[b]; }
    }
}

__global__ __launch_bounds__(1024) void scan_fixup_kernel(
    int* __restrict__ cursor, const int* __restrict__ boff)
{
    const int idx = blockIdx.x * 1024 + threadIdx.x;
    if (idx < N_NODES) cursor[idx] += boff[blockIdx.x];
}

__global__ __launch_bounds__(256) void scatter_kernel(
    const int* __restrict__ edge_dst, int* __restrict__ cursor,
    int* __restrict__ sorted_eid)
{
    const int e = blockIdx.x * 256 + threadIdx.x;
    if (e < E_EDGES) {
        const int p = atomicAdd(&cursor[edge_dst[e]], 1);
        sorted_eid[p] = e;
    }
}

// ---------------------------------------------------------------------------
// Kernel B: per-edge, dst-sorted, 64 edges/block, 4 waves.
// fc1/fc2 via v_dot2_f32_f16 (fp16 inputs, fp32 accumulate).
// LDS ~38.5 KB -> 4 blocks/CU. DPP reductions for edge_out.
// ---------------------------------------------------------------------------
__global__ __launch_bounds__(256, 4) void edge_kernel(
    const float* __restrict__ ws_f,
    const int* __restrict__ edge_src, const int* __restrict__ edge_dst,
    const float* __restrict__ edge_attr, const float* __restrict__ edge_scalars,
    const float* __restrict__ fc_w1, const float* __restrict__ fc_w2,
    const float* __restrict__ w_se0a, const float* __restrict__ w_se0b,
    const float* __restrict__ w_se1a, const float* __restrict__ w_se1b,
    const int* __restrict__ sorted_eid,
    float* __restrict__ nacc, float* __restrict__ edge_out)
{
    __shared__ __align__(16) _Float16 sW1p[1024];   // 2 KB  [kp][j] k-pairs
    __shared__ __align__(16) _Float16 sESh[64 * 22];// 2816 B [e][k], stride 22
    __shared__ __align__(16) _Float16 sW2p[8192];   // 16 KB [kp][c] k-pairs
    __shared__ __align__(16) _Float16 sUN[8192];    // 16 KB union: HT[e][j] s66 | Wt[e][c] s128
    __shared__ __align__(16) float sEA[64 * 4];
    __shared__ int sSRC[64];
    __shared__ int sDST[64];
    __shared__ int sEID[64];

    const int t    = threadIdx.x;
    const int lane = t & 63;
    const int wv   = t >> 6;
    const int e0   = blockIdx.x * 64;

    // ---- stage ----
    if (t < 128) {      // W1 -> interleaved k-pairs fp16
        const int kp = t >> 4, j4 = (t & 15) * 4;
        float4 a = *(const float4*)&fc_w1[(2 * kp) * 64 + j4];
        float4 b = *(const float4*)&fc_w1[(2 * kp + 1) * 64 + j4];
        f16x8 p;
        p[0]=(_Float16)a.x; p[1]=(_Float16)b.x; p[2]=(_Float16)a.y; p[3]=(_Float16)b.y;
        p[4]=(_Float16)a.z; p[5]=(_Float16)b.z; p[6]=(_Float16)a.w; p[7]=(_Float16)b.w;
        *(f16x8*)&sW1p[(kp * 64 + j4) * 2] = p;
    }
    #pragma unroll
    for (int i = 0; i < 4; ++i) {   // W2 -> interleaved k-pairs fp16
        const int u  = t + i * 256;
        const int kp = u >> 5, c4 = (u & 31) * 4;
        float4 a = *(const float4*)&fc_w2[(size_t)(2 * kp) * 128 + c4];
        float4 b = *(const float4*)&fc_w2[(size_t)(2 * kp + 1) * 128 + c4];
        f16x8 p;
        p[0]=(_Float16)a.x; p[1]=(_Float16)b.x; p[2]=(_Float16)a.y; p[3]=(_Float16)b.y;
        p[4]=(_Float16)a.z; p[5]=(_Float16)b.z; p[6]=(_Float16)a.w; p[7]=(_Float16)b.w;
        *(f16x8*)&sW2p[(kp * 128 + c4) * 2] = p;
    }
    {   // edge_scalars gather -> fp16, stride 22
        const int e = t >> 2, k4 = t & 3;
        const int eid = sorted_eid[e0 + e];
        float4 v = ((const float4*)edge_scalars)[(size_t)eid * 4 + k4];
        f16x2 p0 = {(_Float16)v.x, (_Float16)v.y};
        f16x2 p1 = {(_Float16)v.z, (_Float16)v.w};
        *(f16x2*)&sESh[e * 22 + k4 * 4]     = p0;
        *(f16x2*)&sESh[e * 22 + k4 * 4 + 2] = p1;
    }
    if (t < 64) {
        const int eid = sorted_eid[e0 + t];
        *(float4*)&sEA[t * 4] = ((const float4*)edge_attr)[eid];
        sEID[t] = eid;
    } else if (t < 128) {
        sSRC[t - 64] = edge_src[sorted_eid[e0 + (t - 64)]];
    } else if (t < 192) {
        sDST[t - 128] = edge_dst[sorted_eid[e0 + (t - 128)]];
    }
    __syncthreads();

    _Float16* sHT = sUN;            // HT[e][j], stride 66 halfs

    // ---- fc1: h[e][j] = sin(0.25 * es[e] @ W1[:,j]) via dot2 ----
    {
        const int e = lane, j0 = wv * 16;
        float acc[16];
        #pragma unroll
        for (int i = 0; i < 16; ++i) acc[i] = 0.f;
        #pragma unroll
        for (int kp = 0; kp < 8; ++kp) {
            const f16x2 es2 = *(const f16x2*)&sESh[e * 22 + kp * 2];
            const f16x2* wr = (const f16x2*)&sW1p[(kp * 64 + j0) * 2];
            #pragma unroll
            for (int i = 0; i < 16; ++i) acc[i] = dot2(es2, wr[i], acc[i]);
        }
        #pragma unroll
        for (int i = 0; i < 8; ++i) {
            f16x2 hh = {(_Float16)__sinf(acc[2 * i] * FC1_S),
                        (_Float16)__sinf(acc[2 * i + 1] * FC1_S)};
            *(f16x2*)&sHT[e * 66 + j0 + 2 * i] = hh;
        }
    }
    __syncthreads();

    // ---- fc2: w[e][c] = 0.125 * sum_j h[e][j] W2[j][c]; dot2, 8r x 4c/thread ----
    float wacc[8][4];
    #pragma unroll
    for (int r = 0; r < 8; ++r)
        #pragma unroll
        for (int c = 0; c < 4; ++c) wacc[r][c] = 0.f;
    const int c0 = (t & 31) * 4;
    const int r0 = (t >> 5) * 8;
    for (int kp = 0; kp < 32; ++kp) {
        f16x8 wp8 = *(const f16x8*)&sW2p[(kp * 128 + c0) * 2];
        f16x2 wp[4] = {{wp8[0], wp8[1]}, {wp8[2], wp8[3]},
                       {wp8[4], wp8[5]}, {wp8[6], wp8[7]}};
        f16x2 h2[8];
        #pragma unroll
        for (int r = 0; r < 8; ++r)
            h2[r] = *(const f16x2*)&sHT[(r0 + r) * 66 + kp * 2];
        #pragma unroll
        for (int r = 0; r < 8; ++r)
            #pragma unroll
            for (int c = 0; c < 4; ++c) wacc[r][c] = dot2(h2[r], wp[c], wacc[r][c]);
    }
    __syncthreads();            // HT reads done; overwrite union

    _Float16* sWt = sUN;        // Wt[e][c] fp16, stride 128
    {
        #pragma unroll
        for (int r = 0; r < 8; ++r) {
            f16x4 v;
            v[0] = (_Float16)(wacc[r][0] * FC2_S);
            v[1] = (_Float16)(wacc[r][1] * FC2_S);
            v[2] = (_Float16)(wacc[r][2] * FC2_S);
            v[3] = (_Float16)(wacc[r][3] * FC2_S);
            *(f16x4*)&sWt[(r0 + r) * 128 + c0] = v;
        }
    }
    __syncthreads();

    // ---- message phase: 16 sorted edges/wave, register accumulation ----
    const float se0a = w_se0a[lane], se0b = w_se0b[lane];
    const float se1a = w_se1a[lane], se1b = w_se1b[lane];
    const bool hi = lane >= 32;
    const int  u  = lane - 32;
    const int idxA = hi ? (32 + 3 * u) : lane;
    const int idxB = hi ? (33 + 3 * u) : lane;
    const int idxC = hi ? (34 + 3 * u) : lane;
    const int col1 = hi ? (96 + u) : lane;        // wD[u] | wA[l]
    const int col2 = hi ? (64 + u) : (32 + lane); // wC[u] | wB[l]

    int   cur = -1;
    float am0 = 0.f, axx = 0.f, ayy = 0.f, azz = 0.f;

    for (int b = 0; b < 4; ++b) {
        float ga[4], gb[4], gc[4];
        #pragma unroll
        for (int i = 0; i < 4; ++i) {
            const int el = wv * 16 + b * 4 + i;
            const float* fr = ws_f + (size_t)sSRC[el] * 128;
            ga[i] = fr[idxA]; gb[i] = fr[idxB]; gc[i] = fr[idxC];
        }
        #pragma unroll
        for (int i = 0; i < 4; ++i) {
            const int el  = wv * 16 + b * 4 + i;
            const int dst = sDST[el];
            const float ea0 = sEA[el * 4 + 0];
            const float e1x = sEA[el * 4 + 1];
            const float e1y = sEA[el * 4 + 2];
            const float e1z = sEA[el * 4 + 3];
            const float w1v = (float)sWt[el * 128 + col1];
            const float w2v = (float)sWt[el * 128 + col2];

            float mid0, m1x, m1y, m1z;
            if (!hi) {                       // lanes 0..31: mA, mB
                mid0 = w1v * ga[i] * ea0;
                const float wbg = w2v * ga[i];
                m1x = wbg * e1x; m1y = wbg * e1y; m1z = wbg * e1z;
            } else {                         // lanes 32..63: mD, mC
                const float dot = ga[i] * e1x + gb[i] * e1y + gc[i] * e1z;
                mid0 = w1v * dot * INV_SQRT3;
                const float wce = w2v * ea0;
                m1x = wce * ga[i]; m1y = wce * gb[i]; m1z = wce * gc[i];
            }

            if (dst != cur) {               // segment flush (dst wave-uniform)
                if (cur >= 0) {
                    float* np_ = nacc + (size_t)cur * 256;
                    atomicAdd(np_ + lane, am0);
                    atomicAdd(np_ + 64 + lane * 3 + 0, axx);
                    atomicAdd(np_ + 64 + lane * 3 + 1, ayy);
                    atomicAdd(np_ + 64 + lane * 3 + 2, azz);
                }
                cur = dst; am0 = axx = ayy = azz = 0.f;
            }
            am0 += mid0; axx += m1x; ayy += m1y; azz += m1z;

            // edge self-interaction: 5 DPP reductions (all VALU)
            const float dotm = m1x * e1x + m1y * e1y + m1z * e1z;
            const float s0 = wave_reduce_dpp(mid0 * se0a * ea0 + dotm * se0b * INV_SQRT3);
            const float s1 = wave_reduce_dpp(mid0 * se1a);
            const float s2 = wave_reduce_dpp(m1x * se1b);
            const float s3 = wave_reduce_dpp(m1y * se1b);
            const float s4 = wave_reduce_dpp(m1z * se1b);

            if (lane == 0) {
                float4 o;
                o.x = ea0 + s0 * S_SE * INV_NN;
                o.y = e1x + (s1 * e1x + s2 * ea0) * S_SE * INV_NN;
                o.z = e1y + (s1 * e1y + s3 * ea0) * S_SE * INV_NN;
                o.w = e1z + (s1 * e1z + s4 * ea0) * S_SE * INV_NN;
                *(float4*)&edge_out[(size_t)sEID[el] * 4] = o;
            }
        }
    }
    if (cur >= 0) {
        float* np_ = nacc + (size_t)cur * 256;
        atomicAdd(np_ + lane, am0);
        atomicAdd(np_ + 64 + lane * 3 + 0, axx);
        atomicAdd(np_ + 64 + lane * 3 + 1, ayy);
        atomicAdd(np_ + 64 + lane * 3 + 2, azz);
    }
}

// ---------------------------------------------------------------------------
// Kernel C: per-node post; 8 nodes/block, weight column in registers,
// alpha via one DPP reduction per node (wave 0).
// ---------------------------------------------------------------------------
__global__ __launch_bounds__(128) void node_post_kernel(
    const float* __restrict__ nacc, const float* __restrict__ node_attr,
    const float* __restrict__ w_lin2_0, const float* __restrict__ w_lin2_1,
    const float* __restrict__ w_alpha, float* __restrict__ out)
{
    const int n0 = blockIdx.x * 8, t = threadIdx.x;
    __shared__ __align__(16) float sn[8 * 256];
    __shared__ float salpha[8];
    const float4* src = (const float4*)(nacc + (size_t)n0 * 256);
    #pragma unroll
    for (int i = 0; i < 4; ++i) ((float4*)sn)[t + i * 128] = src[t + i * 128];
    __syncthreads();

    if (t < 64) {
        const float wa = w_alpha[t];
        #pragma unroll
        for (int k = 0; k < 8; ++k) {
            const float r = wave_reduce_dpp(sn[k * 256 + t] * wa);
            if (t == 0) salpha[k] = r;
        }
    }
    __syncthreads();

    float wcol[64];
    int m = 0;
    if (t < 32) {
        #pragma unroll
        for (int u = 0; u < 64; ++u) wcol[u] = w_lin2_0[u * 32 + t];
    } else {
        const int j = t - 32; const int w = j / 3; m = j % 3;
        #pragma unroll
        for (int u = 0; u < 64; ++u) wcol[u] = w_lin2_1[u * 32 + w];
    }
    #pragma unroll
    for (int k = 0; k < 8; ++k) {
        const float* s = sn + k * 256;
        float acc = 0.f;
        if (t < 32) {
            #pragma unroll
            for (int u = 0; u < 64; ++u) acc += s[u] * wcol[u];
        } else {
            #pragma unroll
            for (int u = 0; u < 64; ++u) acc += s[64 + u * 3 + m] * wcol[u];
        }
        const float a  = node_attr[n0 + k];
        const float sc = a * S_MID * INV_NN;
        const size_t o = (size_t)(n0 + k) * 128 + t;
        out[o] = out[o] + (salpha[k] * sc) * (acc * sc);
    }
}

extern "C" void kernel_launch(void* const* d_in, const int* in_sizes, int n_in,
                              void* d_out, int out_size, void* d_ws, size_t ws_size,
                              hipStream_t stream)
{
    const float* node_input   = (const float*)d_in[0];
    const float* node_attr    = (const float*)d_in[1];
    const int*   edge_src     = (const int*)d_in[2];
    const int*   edge_dst     = (const int*)d_in[3];
    const float* edge_attr    = (const float*)d_in[4];
    const float* edge_scalars = (const float*)d_in[5];
    const float* w_sc0        = (const float*)d_in[6];
    const float* w_sc1        = (const float*)d_in[7];
    const float* w_lin1_0     = (const float*)d_in[8];
    const float* w_lin1_1     = (const float*)d_in[9];
    const float* fc_w1        = (const float*)d_in[10];
    const float* fc_w2        = (const float*)d_in[11];
    const float* w_lin2_0     = (const float*)d_in[12];
    const float* w_lin2_1     = (const float*)d_in[13];
    const float* w_alpha      = (const float*)d_in[14];
    const float* w_se0a       = (const float*)d_in[15];
    const float* w_se0b       = (const float*)d_in[16];
    const float* w_se1a       = (const float*)d_in[17];
    const float* w_se1b       = (const float*)d_in[18];

    float* out      = (float*)d_out;
    float* edge_out = out + (size_t)N_NODES * 128;

    float* ws_f   = (float*)d_ws;                          // N*128 f
    float* nacc   = ws_f + (size_t)N_NODES * 128;          // N*256 f
    int*   counts = (int*)(nacc + (size_t)N_NODES * 256);  // N
    int*   cursor = counts + N_NODES;                      // N
    int*   sid    = cursor + N_NODES;                      // E
    int*   bsum   = sid + E_EDGES;                         // 64
    int*   boff   = bsum + 64;                             // 64

    hipMemsetAsync(nacc, 0,
        ((size_t)N_NODES * 256 + N_NODES) * sizeof(float), stream);  // nacc+counts

    node_pre_kernel<<<N_NODES / 8, 256, 0, stream>>>(
        node_input, node_attr, w_sc0, w_sc1, w_lin1_0, w_lin1_1, out, ws_f);

    hist_kernel<<<(E_EDGES + 255) / 256, 256, 0, stream>>>(edge_dst, counts);
    scan_block_kernel<<<49, 1024, 0, stream>>>(counts, cursor, bsum);
    scan_bsum_kernel<<<1, 64, 0, stream>>>(bsum, boff);
    scan_fixup_kernel<<<49, 1024, 0, stream>>>(cursor, boff);
    scatter_kernel<<<(E_EDGES + 255) / 256, 256, 0, stream>>>(edge_dst, cursor, sid);

    edge_kernel<<<E_EDGES / 64, 256, 0, stream>>>(
        ws_f, edge_src, edge_dst, edge_attr, edge_scalars, fc_w1, fc_w2,
        w_se0a, w_se0b, w_se1a, w_se1b, sid, nacc, edge_out);

    node_post_kernel<<<N_NODES / 8, 128, 0, stream>>>(
        nacc, node_attr, w_lin2_0, w_lin2_1, w_alpha, out);
}

// Round 5
// 418.353 us; speedup vs baseline: 2.7599x; 1.0274x over previous
//
#include <hip/hip_runtime.h>
#include <math.h>

#define N_NODES 50000
#define E_EDGES 400000
#define NPRE_BLOCKS 6250          // N_NODES/8
#define NHIST_BLOCKS 1563         // ceil(E/256)

typedef _Float16 f16x2 __attribute__((ext_vector_type(2)));
typedef _Float16 f16x4 __attribute__((ext_vector_type(4)));
typedef _Float16 f16x8 __attribute__((ext_vector_type(8)));
typedef float    f32x4 __attribute__((ext_vector_type(4)));

static constexpr float S_IN      = 0.17677669529663687f;   // 1/sqrt(32)
static constexpr float S_MID     = 0.125f;                 // 1/sqrt(64)
static constexpr float S_SE      = 0.08838834764831843f;   // 1/sqrt(128)
static constexpr float INV_NN    = 0.35355339059327373f;   // 1/sqrt(8)
static constexpr float INV_SQRT3 = 0.5773502691896258f;
static constexpr float FC1_S     = 0.25f;                  // 1/sqrt(16)
static constexpr float FC2_S     = 0.125f;                 // 1/sqrt(64)

// 64-lane sum via DPP (VALU pipe, no DS): row_shr 1/2/4/8, bcast15, bcast31.
__device__ inline float wave_reduce_dpp(float v) {
    int x;
    x = __builtin_amdgcn_update_dpp(0, __float_as_int(v), 0x111, 0xf, 0xf, true); v += __int_as_float(x);
    x = __builtin_amdgcn_update_dpp(0, __float_as_int(v), 0x112, 0xf, 0xf, true); v += __int_as_float(x);
    x = __builtin_amdgcn_update_dpp(0, __float_as_int(v), 0x114, 0xf, 0xf, true); v += __int_as_float(x);
    x = __builtin_amdgcn_update_dpp(0, __float_as_int(v), 0x118, 0xf, 0xf, true); v += __int_as_float(x);
    x = __builtin_amdgcn_update_dpp(0, __float_as_int(v), 0x142, 0xa, 0xf, true); v += __int_as_float(x);
    x = __builtin_amdgcn_update_dpp(0, __float_as_int(v), 0x143, 0xc, 0xf, true); v += __int_as_float(x);
    return __int_as_float(__builtin_amdgcn_readlane(__float_as_int(v), 63));
}

// ---------------------------------------------------------------------------
// Kernel A (fused): blocks [0,NPRE) do per-node precompute (8 nodes/block);
// blocks [NPRE, NPRE+NHIST) do the dst histogram. Independent work, one launch.
// ---------------------------------------------------------------------------
__global__ __launch_bounds__(256) void pre_hist_kernel(
    const float* __restrict__ node_input, const float* __restrict__ node_attr,
    const float* __restrict__ w_sc0, const float* __restrict__ w_sc1,
    const float* __restrict__ w_lin1_0, const float* __restrict__ w_lin1_1,
    float* __restrict__ out_self, float* __restrict__ ws_f,
    const int* __restrict__ edge_dst, int* __restrict__ counts)
{
    const int t = threadIdx.x;
    if (blockIdx.x >= NPRE_BLOCKS) {          // histogram role
        const int e = (blockIdx.x - NPRE_BLOCKS) * 256 + t;
        if (e < E_EDGES) atomicAdd(&counts[edge_dst[e]], 1);
        return;
    }
    const int n0 = blockIdx.x * 8;
    __shared__ __align__(16) float sx[8 * 128];
    __shared__ float sa[8];
    ((float4*)sx)[t] = ((const float4*)(node_input + (size_t)n0 * 128))[t];
    if (t < 8) sa[t] = node_attr[n0 + t];
    __syncthreads();

    const int half = t >> 7;
    const int idx  = t & 127;
    float wcol[32];
    int m = 0;
    if (idx < 32) {
        const float* __restrict__ W = half ? w_lin1_0 : w_sc0;
        #pragma unroll
        for (int u = 0; u < 32; ++u) wcol[u] = W[u * 32 + idx];
    } else {
        const float* __restrict__ W = half ? w_lin1_1 : w_sc1;
        const int j = idx - 32;
        const int w = j / 3; m = j % 3;
        #pragma unroll
        for (int u = 0; u < 32; ++u) wcol[u] = W[u * 32 + w];
    }
    float* __restrict__ dstp = half ? ws_f : out_self;
    #pragma unroll
    for (int k = 0; k < 8; ++k) {
        const float* x = sx + k * 128;
        float acc = 0.f;
        if (idx < 32) {
            #pragma unroll
            for (int u = 0; u < 32; ++u) acc += x[u] * wcol[u];
        } else {
            #pragma unroll
            for (int u = 0; u < 32; ++u) acc += x[32 + u * 3 + m] * wcol[u];
        }
        dstp[(size_t)(n0 + k) * 128 + idx] = acc * sa[k] * S_IN;
    }
}

// ---------------------------------------------------------------------------
// Sort by dst: block scan -> fixup(with inline 49-prefix) -> scatter
// ---------------------------------------------------------------------------
__global__ __launch_bounds__(1024) void scan_block_kernel(
    const int* __restrict__ counts, int* __restrict__ cursor, int* __restrict__ bsum)
{
    __shared__ int sd[1024];
    const int t   = threadIdx.x;
    const int idx = blockIdx.x * 1024 + t;
    const int c   = (idx < N_NODES) ? counts[idx] : 0;
    sd[t] = c;
    __syncthreads();
    for (int off = 1; off < 1024; off <<= 1) {
        const int v = (t >= off) ? sd[t - off] : 0;
        __syncthreads();
        sd[t] += v;
        __syncthreads();
    }
    if (idx < N_NODES) cursor[idx] = sd[t] - c;   // block-local exclusive
    if (t == 1023) bsum[blockIdx.x] = sd[1023];
}

__global__ __launch_bounds__(1024) void scan_fixup_kernel(
    int* __restrict__ cursor, const int* __restrict__ bsum)
{
    __shared__ int boff_s;
    const int t = threadIdx.x;
    if (t < 64) {                      // prefix of bsum[0..blockIdx-1], one wave
        int v = (t < (int)blockIdx.x) ? bsum[t] : 0;   // blockIdx <= 48 < 64
        #pragma unroll
        for (int off = 32; off >= 1; off >>= 1) v += __shfl_down(v, off, 64);
        if (t == 0) boff_s = v;
    }
    __syncthreads();
    const int idx = blockIdx.x * 1024 + t;
    if (idx < N_NODES) cursor[idx] += boff_s;
}

__global__ __launch_bounds__(256) void scatter_kernel(
    const int* __restrict__ edge_dst, int* __restrict__ cursor,
    int* __restrict__ sorted_eid)
{
    const int e = blockIdx.x * 256 + threadIdx.x;
    if (e < E_EDGES) {
        const int p = atomicAdd(&cursor[edge_dst[e]], 1);
        sorted_eid[p] = e;
    }
}

// ---------------------------------------------------------------------------
// Kernel B: per-edge, dst-sorted, 64 edges/block, 4 waves.
// fc1: [64x16]@[16x64] via mfma_f32_16x16x32_f16 (K zero-padded to 32).
// fc2: [64x64]@[64x128] via mfma_f32_16x16x32_f16, 2 K-steps.
// LDS arena (halfs): W2T[128][72] @0 (9216) | HT[64][72] @9216 (4608)
//                    ES[64][40] @13824 (2560) | W1T[64][40] @16384 (2560)
// Wt[64][130] fp16 unions over W2T region after fc2. Total ~39.7 KB -> 4 blk/CU.
// ---------------------------------------------------------------------------
__global__ __launch_bounds__(256, 4) void edge_kernel(
    const float* __restrict__ ws_f,
    const int* __restrict__ edge_src, const int* __restrict__ edge_dst,
    const float* __restrict__ edge_attr, const float* __restrict__ edge_scalars,
    const float* __restrict__ fc_w1, const float* __restrict__ fc_w2,
    const float* __restrict__ w_se0a, const float* __restrict__ w_se0b,
    const float* __restrict__ w_se1a, const float* __restrict__ w_se1b,
    const int* __restrict__ sorted_eid,
    float* __restrict__ nacc, float* __restrict__ edge_out)
{
    __shared__ __align__(16) _Float16 sArena[18944];
    __shared__ __align__(16) float sEA[64 * 4];
    __shared__ int sSRC[64];
    __shared__ int sDST[64];
    __shared__ int sEID[64];

    _Float16* __restrict__ sW2T = sArena;            // [c][k] stride 72
    _Float16* __restrict__ sHT  = sArena + 9216;     // [e][k] stride 72
    _Float16* __restrict__ sES  = sArena + 13824;    // [e][k] stride 40 (k<16 data, 16..31 zero)
    _Float16* __restrict__ sW1T = sArena + 16384;    // [j][k] stride 40

    const int t    = threadIdx.x;
    const int lane = t & 63;
    const int wv   = t >> 6;
    const int quad = lane >> 4;
    const int mm   = lane & 15;
    const int e0   = blockIdx.x * 64;

    // ---- stage ----
    {   // W1 -> W1T[j][k] fp16, zero-pad k=16..31
        const int k = t >> 4, n4 = (t & 15) * 4;
        float4 v = ((const float4*)fc_w1)[t];
        sW1T[(n4 + 0) * 40 + k] = (_Float16)v.x;
        sW1T[(n4 + 1) * 40 + k] = (_Float16)v.y;
        sW1T[(n4 + 2) * 40 + k] = (_Float16)v.z;
        sW1T[(n4 + 3) * 40 + k] = (_Float16)v.w;
        const f16x4 z4 = {(_Float16)0.f, (_Float16)0.f, (_Float16)0.f, (_Float16)0.f};
        *(f16x4*)&sW1T[(t >> 2) * 40 + 16 + (t & 3) * 4] = z4;
    }
    #pragma unroll
    for (int i = 0; i < 8; ++i) {   // W2 -> W2T[c][k] fp16
        const int u = t + i * 256;
        const int k = u >> 5, c4 = (u & 31) * 4;
        float4 v = ((const float4*)fc_w2)[u];
        sW2T[(c4 + 0) * 72 + k] = (_Float16)v.x;
        sW2T[(c4 + 1) * 72 + k] = (_Float16)v.y;
        sW2T[(c4 + 2) * 72 + k] = (_Float16)v.z;
        sW2T[(c4 + 3) * 72 + k] = (_Float16)v.w;
    }
    {   // edge_scalars gather -> ES[e][k] fp16, zero-pad k=16..31
        const int e = t >> 2, k4 = (t & 3) * 4;
        const int eid = sorted_eid[e0 + e];
        float4 v = ((const float4*)edge_scalars)[(size_t)eid * 4 + (t & 3)];
        f16x4 p = {(_Float16)v.x, (_Float16)v.y, (_Float16)v.z, (_Float16)v.w};
        *(f16x4*)&sES[e * 40 + k4] = p;
        const f16x4 z4 = {(_Float16)0.f, (_Float16)0.f, (_Float16)0.f, (_Float16)0.f};
        *(f16x4*)&sES[e * 40 + 16 + k4] = z4;
    }
    if (t < 64) {
        const int eid = sorted_eid[e0 + t];
        *(float4*)&sEA[t * 4] = ((const float4*)edge_attr)[eid];
        sEID[t] = eid;
    } else if (t < 128) {
        sSRC[t - 64] = edge_src[sorted_eid[e0 + (t - 64)]];
    } else if (t < 192) {
        sDST[t - 128] = edge_dst[sorted_eid[e0 + (t - 128)]];
    }
    __syncthreads();

    // ---- fc1 via MFMA: h[e][j] = sin(0.25 * es @ W1) ----
    const int eb = wv * 16;
    {
        const f16x8 a_es = *(const f16x8*)&sES[(eb + mm) * 40 + quad * 8];
        #pragma unroll
        for (int jt = 0; jt < 4; ++jt) {
            const f16x8 b = *(const f16x8*)&sW1T[(jt * 16 + mm) * 40 + quad * 8];
            f32x4 d = {0.f, 0.f, 0.f, 0.f};
            d = __builtin_amdgcn_mfma_f32_16x16x32_f16(a_es, b, d, 0, 0, 0);
            #pragma unroll
            for (int r = 0; r < 4; ++r)
                sHT[(eb + quad * 4 + r) * 72 + jt * 16 + mm] =
                    (_Float16)__sinf(d[r] * FC1_S);
        }
    }
    __syncthreads();

    // ---- fc2 via MFMA: w[e][c] = 0.125 * h @ W2 ; all 8 c-tiles in regs ----
    f32x4 dacc[8];
    {
        const f16x8 a_lo = *(const f16x8*)&sHT[(eb + mm) * 72 + quad * 8];
        const f16x8 a_hi = *(const f16x8*)&sHT[(eb + mm) * 72 + 32 + quad * 8];
        #pragma unroll
        for (int ct = 0; ct < 8; ++ct) {
            const f16x8 b_lo = *(const f16x8*)&sW2T[(ct * 16 + mm) * 72 + quad * 8];
            const f16x8 b_hi = *(const f16x8*)&sW2T[(ct * 16 + mm) * 72 + 32 + quad * 8];
            f32x4 d = {0.f, 0.f, 0.f, 0.f};
            d = __builtin_amdgcn_mfma_f32_16x16x32_f16(a_lo, b_lo, d, 0, 0, 0);
            d = __builtin_amdgcn_mfma_f32_16x16x32_f16(a_hi, b_hi, d, 0, 0, 0);
            dacc[ct] = d;
        }
    }
    __syncthreads();            // all W2T reads done; overwrite with Wt

    _Float16* __restrict__ sWt = sArena;   // Wt[e][c] fp16, stride 130
    {
        #pragma unroll
        for (int ct = 0; ct < 8; ++ct)
            #pragma unroll
            for (int r = 0; r < 4; ++r)
                sWt[(eb + quad * 4 + r) * 130 + ct * 16 + mm] =
                    (_Float16)(dacc[ct][r] * FC2_S);
    }
    __syncthreads();

    // ---- message phase: 16 sorted edges/wave, register accumulation ----
    const float se0a = w_se0a[lane], se0b = w_se0b[lane];
    const float se1a = w_se1a[lane], se1b = w_se1b[lane];
    const bool hi = lane >= 32;
    const int  u  = lane - 32;
    const int idxA = hi ? (32 + 3 * u) : lane;
    const int idxB = hi ? (33 + 3 * u) : lane;
    const int idxC = hi ? (34 + 3 * u) : lane;
    const int col1 = hi ? (96 + u) : lane;        // wD[u] | wA[l]
    const int col2 = hi ? (64 + u) : (32 + lane); // wC[u] | wB[l]

    int   cur = -1;
    float am0 = 0.f, axx = 0.f, ayy = 0.f, azz = 0.f;

    for (int b = 0; b < 4; ++b) {
        float ga[4], gb[4], gc[4];
        #pragma unroll
        for (int i = 0; i < 4; ++i) {
            const int el = wv * 16 + b * 4 + i;
            const float* fr = ws_f + (size_t)sSRC[el] * 128;
            ga[i] = fr[idxA]; gb[i] = fr[idxB]; gc[i] = fr[idxC];
        }
        #pragma unroll
        for (int i = 0; i < 4; ++i) {
            const int el  = wv * 16 + b * 4 + i;
            const int dst = sDST[el];
            const float ea0 = sEA[el * 4 + 0];
            const float e1x = sEA[el * 4 + 1];
            const float e1y = sEA[el * 4 + 2];
            const float e1z = sEA[el * 4 + 3];
            const float w1v = (float)sWt[el * 130 + col1];
            const float w2v = (float)sWt[el * 130 + col2];

            float mid0, m1x, m1y, m1z;
            if (!hi) {                       // lanes 0..31: mA, mB
                mid0 = w1v * ga[i] * ea0;
                const float wbg = w2v * ga[i];
                m1x = wbg * e1x; m1y = wbg * e1y; m1z = wbg * e1z;
            } else {                         // lanes 32..63: mD, mC
                const float dot = ga[i] * e1x + gb[i] * e1y + gc[i] * e1z;
                mid0 = w1v * dot * INV_SQRT3;
                const float wce = w2v * ea0;
                m1x = wce * ga[i]; m1y = wce * gb[i]; m1z = wce * gc[i];
            }

            if (dst != cur) {               // segment flush (dst wave-uniform)
                if (cur >= 0) {
                    float* np_ = nacc + (size_t)cur * 256;
                    atomicAdd(np_ + lane, am0);
                    atomicAdd(np_ + 64 + lane * 3 + 0, axx);
                    atomicAdd(np_ + 64 + lane * 3 + 1, ayy);
                    atomicAdd(np_ + 64 + lane * 3 + 2, azz);
                }
                cur = dst; am0 = axx = ayy = azz = 0.f;
            }
            am0 += mid0; axx += m1x; ayy += m1y; azz += m1z;

            // edge self-interaction: 5 DPP reductions (all VALU)
            const float dotm = m1x * e1x + m1y * e1y + m1z * e1z;
            const float s0 = wave_reduce_dpp(mid0 * se0a * ea0 + dotm * se0b * INV_SQRT3);
            const float s1 = wave_reduce_dpp(mid0 * se1a);
            const float s2 = wave_reduce_dpp(m1x * se1b);
            const float s3 = wave_reduce_dpp(m1y * se1b);
            const float s4 = wave_reduce_dpp(m1z * se1b);

            if (lane == 0) {
                float4 o;
                o.x = ea0 + s0 * S_SE * INV_NN;
                o.y = e1x + (s1 * e1x + s2 * ea0) * S_SE * INV_NN;
                o.z = e1y + (s1 * e1y + s3 * ea0) * S_SE * INV_NN;
                o.w = e1z + (s1 * e1z + s4 * ea0) * S_SE * INV_NN;
                *(float4*)&edge_out[(size_t)sEID[el] * 4] = o;
            }
        }
    }
    if (cur >= 0) {
        float* np_ = nacc + (size_t)cur * 256;
        atomicAdd(np_ + lane, am0);
        atomicAdd(np_ + 64 + lane * 3 + 0, axx);
        atomicAdd(np_ + 64 + lane * 3 + 1, ayy);
        atomicAdd(np_ + 64 + lane * 3 + 2, azz);
    }
}

// ---------------------------------------------------------------------------
// Kernel C: per-node post; 8 nodes/block, weight column in registers.
// ---------------------------------------------------------------------------
__global__ __launch_bounds__(128) void node_post_kernel(
    const float* __restrict__ nacc, const float* __restrict__ node_attr,
    const float* __restrict__ w_lin2_0, const float* __restrict__ w_lin2_1,
    const float* __restrict__ w_alpha, float* __restrict__ out)
{
    const int n0 = blockIdx.x * 8, t = threadIdx.x;
    __shared__ __align__(16) float sn[8 * 256];
    __shared__ float salpha[8];
    const float4* src = (const float4*)(nacc + (size_t)n0 * 256);
    #pragma unroll
    for (int i = 0; i < 4; ++i) ((float4*)sn)[t + i * 128] = src[t + i * 128];
    __syncthreads();

    if (t < 64) {
        const float wa = w_alpha[t];
        #pragma unroll
        for (int k = 0; k < 8; ++k) {
            const float r = wave_reduce_dpp(sn[k * 256 + t] * wa);
            if (t == 0) salpha[k] = r;
        }
    }
    __syncthreads();

    float wcol[64];
    int m = 0;
    if (t < 32) {
        #pragma unroll
        for (int u = 0; u < 64; ++u) wcol[u] = w_lin2_0[u * 32 + t];
    } else {
        const int j = t - 32; const int w = j / 3; m = j % 3;
        #pragma unroll
        for (int u = 0; u < 64; ++u) wcol[u] = w_lin2_1[u * 32 + w];
    }
    #pragma unroll
    for (int k = 0; k < 8; ++k) {
        const float* s = sn + k * 256;
        float acc = 0.f;
        if (t < 32) {
            #pragma unroll
            for (int u = 0; u < 64; ++u) acc += s[u] * wcol[u];
        } else {
            #pragma unroll
            for (int u = 0; u < 64; ++u) acc += s[64 + u * 3 + m] * wcol[u];
        }
        const float a  = node_attr[n0 + k];
        const float sc = a * S_MID * INV_NN;
        const size_t o = (size_t)(n0 + k) * 128 + t;
        out[o] = out[o] + (salpha[k] * sc) * (acc * sc);
    }
}

extern "C" void kernel_launch(void* const* d_in, const int* in_sizes, int n_in,
                              void* d_out, int out_size, void* d_ws, size_t ws_size,
                              hipStream_t stream)
{
    const float* node_input   = (const float*)d_in[0];
    const float* node_attr    = (const float*)d_in[1];
    const int*   edge_src     = (const int*)d_in[2];
    const int*   edge_dst     = (const int*)d_in[3];
    const float* edge_attr    = (const float*)d_in[4];
    const float* edge_scalars = (const float*)d_in[5];
    const float* w_sc0        = (const float*)d_in[6];
    const float* w_sc1        = (const float*)d_in[7];
    const float* w_lin1_0     = (const float*)d_in[8];
    const float* w_lin1_1     = (const float*)d_in[9];
    const float* fc_w1        = (const float*)d_in[10];
    const float* fc_w2        = (const float*)d_in[11];
    const float* w_lin2_0     = (const float*)d_in[12];
    const float* w_lin2_1     = (const float*)d_in[13];
    const float* w_alpha      = (const float*)d_in[14];
    const float* w_se0a       = (const float*)d_in[15];
    const float* w_se0b       = (const float*)d_in[16];
    const float* w_se1a       = (const float*)d_in[17];
    const float* w_se1b       = (const float*)d_in[18];

    float* out      = (float*)d_out;
    float* edge_out = out + (size_t)N_NODES * 128;

    float* ws_f   = (float*)d_ws;                          // N*128 f
    float* nacc   = ws_f + (size_t)N_NODES * 128;          // N*256 f
    int*   counts = (int*)(nacc + (size_t)N_NODES * 256);  // N
    int*   cursor = counts + N_NODES;                      // N
    int*   sid    = cursor + N_NODES;                      // E
    int*   bsum   = sid + E_EDGES;                         // 64

    hipMemsetAsync(nacc, 0,
        ((size_t)N_NODES * 256 + N_NODES) * sizeof(float), stream);  // nacc+counts

    pre_hist_kernel<<<NPRE_BLOCKS + NHIST_BLOCKS, 256, 0, stream>>>(
        node_input, node_attr, w_sc0, w_sc1, w_lin1_0, w_lin1_1, out, ws_f,
        edge_dst, counts);

    scan_block_kernel<<<49, 1024, 0, stream>>>(counts, cursor, bsum);
    scan_fixup_kernel<<<49, 1024, 0, stream>>>(cursor, bsum);
    scatter_kernel<<<(E_EDGES + 255) / 256, 256, 0, stream>>>(edge_dst, cursor, sid);

    edge_kernel<<<E_EDGES / 64, 256, 0, stream>>>(
        ws_f, edge_src, edge_dst, edge_attr, edge_scalars, fc_w1, fc_w2,
        w_se0a, w_se0b, w_se1a, w_se1b, sid, nacc, edge_out);

    node_post_kernel<<<N_NODES / 8, 128, 0, stream>>>(
        nacc, node_attr, w_lin2_0, w_lin2_1, w_alpha, out);
}

// Round 6
// 413.124 us; speedup vs baseline: 2.7948x; 1.0127x over previous
//
#include <hip/hip_runtime.h>
#include <math.h>

#define N_NODES 50000
#define E_EDGES 400000
#define NPRE_BLOCKS 6250          // N_NODES/8
#define NHIST_BLOCKS 1563         // ceil(E/256)

typedef _Float16 f16x2 __attribute__((ext_vector_type(2)));
typedef _Float16 f16x4 __attribute__((ext_vector_type(4)));
typedef _Float16 f16x8 __attribute__((ext_vector_type(8)));
typedef float    f32x4 __attribute__((ext_vector_type(4)));

static constexpr float S_IN      = 0.17677669529663687f;   // 1/sqrt(32)
static constexpr float S_MID     = 0.125f;                 // 1/sqrt(64)
static constexpr float S_SE      = 0.08838834764831843f;   // 1/sqrt(128)
static constexpr float INV_NN    = 0.35355339059327373f;   // 1/sqrt(8)
static constexpr float INV_SQRT3 = 0.5773502691896258f;
static constexpr float FC1_S     = 0.25f;                  // 1/sqrt(16)
static constexpr float FC2_S     = 0.125f;                 // 1/sqrt(64)

// 64-lane sum via DPP (VALU pipe, no DS): row_shr 1/2/4/8, bcast15, bcast31.
__device__ inline float wave_reduce_dpp(float v) {
    int x;
    x = __builtin_amdgcn_update_dpp(0, __float_as_int(v), 0x111, 0xf, 0xf, true); v += __int_as_float(x);
    x = __builtin_amdgcn_update_dpp(0, __float_as_int(v), 0x112, 0xf, 0xf, true); v += __int_as_float(x);
    x = __builtin_amdgcn_update_dpp(0, __float_as_int(v), 0x114, 0xf, 0xf, true); v += __int_as_float(x);
    x = __builtin_amdgcn_update_dpp(0, __float_as_int(v), 0x118, 0xf, 0xf, true); v += __int_as_float(x);
    x = __builtin_amdgcn_update_dpp(0, __float_as_int(v), 0x142, 0xa, 0xf, true); v += __int_as_float(x);
    x = __builtin_amdgcn_update_dpp(0, __float_as_int(v), 0x143, 0xc, 0xf, true); v += __int_as_float(x);
    return __int_as_float(__builtin_amdgcn_readlane(__float_as_int(v), 63));
}

// ---------------------------------------------------------------------------
// Kernel A (fused): blocks [0,NPRE) per-node precompute; rest: dst histogram.
// ---------------------------------------------------------------------------
__global__ __launch_bounds__(256) void pre_hist_kernel(
    const float* __restrict__ node_input, const float* __restrict__ node_attr,
    const float* __restrict__ w_sc0, const float* __restrict__ w_sc1,
    const float* __restrict__ w_lin1_0, const float* __restrict__ w_lin1_1,
    float* __restrict__ out_self, float* __restrict__ ws_f,
    const int* __restrict__ edge_dst, int* __restrict__ counts)
{
    const int t = threadIdx.x;
    if (blockIdx.x >= NPRE_BLOCKS) {          // histogram role
        const int e = (blockIdx.x - NPRE_BLOCKS) * 256 + t;
        if (e < E_EDGES) atomicAdd(&counts[edge_dst[e]], 1);
        return;
    }
    const int n0 = blockIdx.x * 8;
    __shared__ __align__(16) float sx[8 * 128];
    __shared__ float sa[8];
    ((float4*)sx)[t] = ((const float4*)(node_input + (size_t)n0 * 128))[t];
    if (t < 8) sa[t] = node_attr[n0 + t];
    __syncthreads();

    const int half = t >> 7;
    const int idx  = t & 127;
    float wcol[32];
    int m = 0;
    if (idx < 32) {
        const float* __restrict__ W = half ? w_lin1_0 : w_sc0;
        #pragma unroll
        for (int u = 0; u < 32; ++u) wcol[u] = W[u * 32 + idx];
    } else {
        const float* __restrict__ W = half ? w_lin1_1 : w_sc1;
        const int j = idx - 32;
        const int w = j / 3; m = j % 3;
        #pragma unroll
        for (int u = 0; u < 32; ++u) wcol[u] = W[u * 32 + w];
    }
    float* __restrict__ dstp = half ? ws_f : out_self;
    #pragma unroll
    for (int k = 0; k < 8; ++k) {
        const float* x = sx + k * 128;
        float acc = 0.f;
        if (idx < 32) {
            #pragma unroll
            for (int u = 0; u < 32; ++u) acc += x[u] * wcol[u];
        } else {
            #pragma unroll
            for (int u = 0; u < 32; ++u) acc += x[32 + u * 3 + m] * wcol[u];
        }
        dstp[(size_t)(n0 + k) * 128 + idx] = acc * sa[k] * S_IN;
    }
}

// ---------------------------------------------------------------------------
// Sort by dst: block scan -> fixup(with inline 49-prefix) -> scatter
// ---------------------------------------------------------------------------
__global__ __launch_bounds__(1024) void scan_block_kernel(
    const int* __restrict__ counts, int* __restrict__ cursor, int* __restrict__ bsum)
{
    __shared__ int sd[1024];
    const int t   = threadIdx.x;
    const int idx = blockIdx.x * 1024 + t;
    const int c   = (idx < N_NODES) ? counts[idx] : 0;
    sd[t] = c;
    __syncthreads();
    for (int off = 1; off < 1024; off <<= 1) {
        const int v = (t >= off) ? sd[t - off] : 0;
        __syncthreads();
        sd[t] += v;
        __syncthreads();
    }
    if (idx < N_NODES) cursor[idx] = sd[t] - c;   // block-local exclusive
    if (t == 1023) bsum[blockIdx.x] = sd[1023];
}

__global__ __launch_bounds__(1024) void scan_fixup_kernel(
    int* __restrict__ cursor, const int* __restrict__ bsum)
{
    __shared__ int boff_s;
    const int t = threadIdx.x;
    if (t < 64) {                      // prefix of bsum[0..blockIdx-1], one wave
        int v = (t < (int)blockIdx.x) ? bsum[t] : 0;   // blockIdx <= 48 < 64
        #pragma unroll
        for (int off = 32; off >= 1; off >>= 1) v += __shfl_down(v, off, 64);
        if (t == 0) boff_s = v;
    }
    __syncthreads();
    const int idx = blockIdx.x * 1024 + t;
    if (idx < N_NODES) cursor[idx] += boff_s;
}

__global__ __launch_bounds__(256) void scatter_kernel(
    const int* __restrict__ edge_dst, int* __restrict__ cursor,
    int* __restrict__ sorted_eid)
{
    const int e = blockIdx.x * 256 + threadIdx.x;
    if (e < E_EDGES) {
        const int p = atomicAdd(&cursor[edge_dst[e]], 1);
        sorted_eid[p] = e;
    }
}

// ---------------------------------------------------------------------------
// Kernel B: per-edge, dst-sorted, 64 edges/block, 4 waves.
// Operand-swapped MFMAs: D-fragment regs run along the contiguous LDS dim ->
// all fragment stores are f16x4 (<=2-way banking, free). se-reductions via
// MFMA over a per-wave 4x264 mid tile x block-constant 16x264 B^T.
// Phase1 arena (halfs): W2T[128][72]@0 | HT[64][72]@9216 | ES[64][40]@13824
//                       | W1T[64][40]@16384  (18944 total)
// Phase2 overlay:       Wt[64][136]@0 | midA 4wv x 4x264 @8704 | BT[16][264]@12928
// ---------------------------------------------------------------------------
__global__ __launch_bounds__(256, 4) void edge_kernel(
    const float* __restrict__ ws_f,
    const int* __restrict__ edge_src, const int* __restrict__ edge_dst,
    const float* __restrict__ edge_attr, const float* __restrict__ edge_scalars,
    const float* __restrict__ fc_w1, const float* __restrict__ fc_w2,
    const float* __restrict__ w_se0a, const float* __restrict__ w_se0b,
    const float* __restrict__ w_se1a, const float* __restrict__ w_se1b,
    const int* __restrict__ sorted_eid,
    float* __restrict__ nacc, float* __restrict__ edge_out)
{
    __shared__ __align__(16) _Float16 sArena[18944];
    __shared__ __align__(16) float sEA[64 * 4];
    __shared__ __align__(16) float sDep[4][36];     // per-wave 8 cols x 4 edges
    __shared__ int sSRC[64];
    __shared__ int sDST[64];
    __shared__ int sEID[64];

    _Float16* __restrict__ sW2T  = sArena;           // [c][k] stride 72
    _Float16* __restrict__ sHT   = sArena + 9216;    // [e][k] stride 72
    _Float16* __restrict__ sES   = sArena + 13824;   // [e][k] stride 40
    _Float16* __restrict__ sW1T  = sArena + 16384;   // [j][k] stride 40
    _Float16* __restrict__ sWt   = sArena;           // ph2: [e][c] stride 136
    _Float16* __restrict__ sMidA = sArena + 8704;    // ph2: wv*1056 + row*264
    _Float16* __restrict__ sBT   = sArena + 12928;   // ph2: [c][k] stride 264

    const int t    = threadIdx.x;
    const int lane = t & 63;
    const int wv   = t >> 6;
    const int quad = lane >> 4;
    const int mm   = lane & 15;
    const int e0   = blockIdx.x * 64;

    // ---- stage ----
    {   // W1 -> W1T[j][k] fp16, zero-pad k=16..31
        const int k = t >> 4, n4 = (t & 15) * 4;
        float4 v = ((const float4*)fc_w1)[t];
        sW1T[(n4 + 0) * 40 + k] = (_Float16)v.x;
        sW1T[(n4 + 1) * 40 + k] = (_Float16)v.y;
        sW1T[(n4 + 2) * 40 + k] = (_Float16)v.z;
        sW1T[(n4 + 3) * 40 + k] = (_Float16)v.w;
        const f16x4 z4 = {(_Float16)0.f, (_Float16)0.f, (_Float16)0.f, (_Float16)0.f};
        *(f16x4*)&sW1T[(t >> 2) * 40 + 16 + (t & 3) * 4] = z4;
    }
    #pragma unroll
    for (int i = 0; i < 8; ++i) {   // W2 -> W2T[c][k] fp16
        const int u = t + i * 256;
        const int k = u >> 5, c4 = (u & 31) * 4;
        float4 v = ((const float4*)fc_w2)[u];
        sW2T[(c4 + 0) * 72 + k] = (_Float16)v.x;
        sW2T[(c4 + 1) * 72 + k] = (_Float16)v.y;
        sW2T[(c4 + 2) * 72 + k] = (_Float16)v.z;
        sW2T[(c4 + 3) * 72 + k] = (_Float16)v.w;
    }
    {   // edge_scalars gather -> ES[e][k] fp16, zero-pad k=16..31
        const int e = t >> 2, k4 = (t & 3) * 4;
        const int eid = sorted_eid[e0 + e];
        float4 v = ((const float4*)edge_scalars)[(size_t)eid * 4 + (t & 3)];
        f16x4 p = {(_Float16)v.x, (_Float16)v.y, (_Float16)v.z, (_Float16)v.w};
        *(f16x4*)&sES[e * 40 + k4] = p;
        const f16x4 z4 = {(_Float16)0.f, (_Float16)0.f, (_Float16)0.f, (_Float16)0.f};
        *(f16x4*)&sES[e * 40 + 16 + k4] = z4;
    }
    if (t < 64) {
        const int eid = sorted_eid[e0 + t];
        *(float4*)&sEA[t * 4] = ((const float4*)edge_attr)[eid];
        sEID[t] = eid;
    } else if (t < 128) {
        sSRC[t - 64] = edge_src[sorted_eid[e0 + (t - 64)]];
    } else if (t < 192) {
        sDST[t - 128] = edge_dst[sorted_eid[e0 + (t - 128)]];
    }
    __syncthreads();

    const int eb = wv * 16;

    // ---- fc1 (swapped): D1[j][e] = W1T . ES^T; store h[e][j] via f16x4 ----
    {
        const f16x8 b_es = *(const f16x8*)&sES[(eb + mm) * 40 + quad * 8];
        #pragma unroll
        for (int jt = 0; jt < 4; ++jt) {
            const f16x8 a_w1 = *(const f16x8*)&sW1T[(jt * 16 + mm) * 40 + quad * 8];
            f32x4 d = {0.f, 0.f, 0.f, 0.f};
            d = __builtin_amdgcn_mfma_f32_16x16x32_f16(a_w1, b_es, d, 0, 0, 0);
            f16x4 hv;
            hv[0] = (_Float16)__sinf(d[0] * FC1_S);
            hv[1] = (_Float16)__sinf(d[1] * FC1_S);
            hv[2] = (_Float16)__sinf(d[2] * FC1_S);
            hv[3] = (_Float16)__sinf(d[3] * FC1_S);
            *(f16x4*)&sHT[(eb + mm) * 72 + jt * 16 + quad * 4] = hv;
        }
    }
    __syncthreads();

    // ---- fc2 (swapped): D2[c][e] = W2T . h^T; keep in regs ----
    f32x4 dacc[8];
    {
        const f16x8 b_lo = *(const f16x8*)&sHT[(eb + mm) * 72 + quad * 8];
        const f16x8 b_hi = *(const f16x8*)&sHT[(eb + mm) * 72 + 32 + quad * 8];
        #pragma unroll
        for (int ct = 0; ct < 8; ++ct) {
            const f16x8 a_lo = *(const f16x8*)&sW2T[(ct * 16 + mm) * 72 + quad * 8];
            const f16x8 a_hi = *(const f16x8*)&sW2T[(ct * 16 + mm) * 72 + 32 + quad * 8];
            f32x4 d = {0.f, 0.f, 0.f, 0.f};
            d = __builtin_amdgcn_mfma_f32_16x16x32_f16(a_lo, b_lo, d, 0, 0, 0);
            d = __builtin_amdgcn_mfma_f32_16x16x32_f16(a_hi, b_hi, d, 0, 0, 0);
            dacc[ct] = d;
        }
    }
    __syncthreads();            // all W2T/HT reads done; overlay phase-2

    // Wt[e][c] store (f16x4, c contiguous per lane) + zero BT
    {
        #pragma unroll
        for (int ct = 0; ct < 8; ++ct) {
            f16x4 v;
            v[0] = (_Float16)(dacc[ct][0] * FC2_S);
            v[1] = (_Float16)(dacc[ct][1] * FC2_S);
            v[2] = (_Float16)(dacc[ct][2] * FC2_S);
            v[3] = (_Float16)(dacc[ct][3] * FC2_S);
            *(f16x4*)&sWt[(eb + mm) * 136 + ct * 16 + quad * 4] = v;
        }
        const f16x8 z8 = {};
        for (int i = t; i < 528; i += 256) *(f16x8*)&sBT[i * 8] = z8;
    }
    __syncthreads();
    {   // fill BT: col 2p gets {se0a|se1b} on comp p, col 2p+1 gets {se1a|se0b}
        const int u = t & 63, p = t >> 6;
        const float ev = (p == 0) ? w_se0a[u] : w_se1b[u];
        const float ov = (p == 0) ? w_se1a[u] : w_se0b[u];
        sBT[(2 * p) * 264 + 4 * u + p]     = (_Float16)ev;
        sBT[(2 * p + 1) * 264 + 4 * u + p] = (_Float16)ov;
    }
    __syncthreads();

    // ---- message phase: 16 sorted edges/wave in 4 batches ----
    const bool hi = lane >= 32;
    const int  u  = lane - 32;
    const int idxA = hi ? (32 + 3 * u) : lane;
    const int idxB = hi ? (33 + 3 * u) : lane;
    const int idxC = hi ? (34 + 3 * u) : lane;
    const int col1 = hi ? (96 + u) : lane;        // wD[u] | wA[l]
    const int col2 = hi ? (64 + u) : (32 + lane); // wC[u] | wB[l]

    int   cur = -1;
    float am0 = 0.f, axx = 0.f, ayy = 0.f, azz = 0.f;
    _Float16* __restrict__ myA = sMidA + wv * 1056;
    const _Float16* __restrict__ arow = myA + (mm & 3) * 264;
    const _Float16* __restrict__ brow = sBT + mm * 264;

    for (int b = 0; b < 4; ++b) {
        float ga[4], gb[4], gc[4];
        #pragma unroll
        for (int i = 0; i < 4; ++i) {
            const int el = eb + b * 4 + i;
            const float* fr = ws_f + (size_t)sSRC[el] * 128;
            ga[i] = fr[idxA]; gb[i] = fr[idxB]; gc[i] = fr[idxC];
        }
        #pragma unroll
        for (int i = 0; i < 4; ++i) {
            const int el  = eb + b * 4 + i;
            const int dst = sDST[el];
            const float ea0 = sEA[el * 4 + 0];
            const float e1x = sEA[el * 4 + 1];
            const float e1y = sEA[el * 4 + 2];
            const float e1z = sEA[el * 4 + 3];
            const float w1v = (float)sWt[el * 136 + col1];
            const float w2v = (float)sWt[el * 136 + col2];

            float mid0, m1x, m1y, m1z;
            if (!hi) {                       // lanes 0..31: mA, mB
                mid0 = w1v * ga[i] * ea0;
                const float wbg = w2v * ga[i];
                m1x = wbg * e1x; m1y = wbg * e1y; m1z = wbg * e1z;
            } else {                         // lanes 32..63: mD, mC
                const float dot = ga[i] * e1x + gb[i] * e1y + gc[i] * e1z;
                mid0 = w1v * dot * INV_SQRT3;
                const float wce = w2v * ea0;
                m1x = wce * ga[i]; m1y = wce * gb[i]; m1z = wce * gc[i];
            }

            if (dst != cur) {               // segment flush (dst wave-uniform)
                if (cur >= 0) {
                    float* np_ = nacc + (size_t)cur * 256;
                    atomicAdd(np_ + lane, am0);
                    atomicAdd(np_ + 64 + lane * 3 + 0, axx);
                    atomicAdd(np_ + 64 + lane * 3 + 1, ayy);
                    atomicAdd(np_ + 64 + lane * 3 + 2, azz);
                }
                cur = dst; am0 = axx = ayy = azz = 0.f;
            }
            am0 += mid0; axx += m1x; ayy += m1y; azz += m1z;

            // mid -> A-tile row i, k = 4*lane + {0,1,2,3}
            f16x4 mv;
            mv[0] = (_Float16)mid0; mv[1] = (_Float16)m1x;
            mv[2] = (_Float16)m1y;  mv[3] = (_Float16)m1z;
            *(f16x4*)&myA[i * 264 + 4 * lane] = mv;
        }

        // se matmul: [4e x 256k] x [256k x 8c], K-loop of 8 MFMAs
        f32x4 d = {0.f, 0.f, 0.f, 0.f};
        #pragma unroll
        for (int ks = 0; ks < 8; ++ks) {
            const f16x8 a  = *(const f16x8*)&arow[ks * 32 + quad * 8];
            const f16x8 bb = *(const f16x8*)&brow[ks * 32 + quad * 8];
            d = __builtin_amdgcn_mfma_f32_16x16x32_f16(a, bb, d, 0, 0, 0);
        }
        if (lane < 8) {                 // quad 0: reg r = edge b*4+r, col = lane
            float4 f4; f4.x = d[0]; f4.y = d[1]; f4.z = d[2]; f4.w = d[3];
            *(float4*)&sDep[wv][lane * 4] = f4;
        }
        if (lane < 4) {                 // lane = edge within batch
            const int el = eb + b * 4 + lane;
            const float c0 = sDep[wv][ 0 + lane], c1 = sDep[wv][ 4 + lane];
            const float c2 = sDep[wv][ 8 + lane], c3 = sDep[wv][12 + lane];
            const float c4 = sDep[wv][16 + lane], c5 = sDep[wv][20 + lane];
            const float c6 = sDep[wv][24 + lane], c7 = sDep[wv][28 + lane];
            const float ea0 = sEA[el * 4 + 0];
            const float e1x = sEA[el * 4 + 1];
            const float e1y = sEA[el * 4 + 2];
            const float e1z = sEA[el * 4 + 3];
            const float s0 = c0 * ea0 + (c3 * e1x + c5 * e1y + c7 * e1z) * INV_SQRT3;
            float4 o;
            o.x = ea0 + s0 * S_SE * INV_NN;
            o.y = e1x + (c1 * e1x + c2 * ea0) * S_SE * INV_NN;
            o.z = e1y + (c1 * e1y + c4 * ea0) * S_SE * INV_NN;
            o.w = e1z + (c1 * e1z + c6 * ea0) * S_SE * INV_NN;
            *(float4*)&edge_out[(size_t)sEID[el] * 4] = o;
        }
    }
    if (cur >= 0) {
        float* np_ = nacc + (size_t)cur * 256;
        atomicAdd(np_ + lane, am0);
        atomicAdd(np_ + 64 + lane * 3 + 0, axx);
        atomicAdd(np_ + 64 + lane * 3 + 1, ayy);
        atomicAdd(np_ + 64 + lane * 3 + 2, azz);
    }
}

// ---------------------------------------------------------------------------
// Kernel C: per-node post; 8 nodes/block, weight column in registers.
// ---------------------------------------------------------------------------
__global__ __launch_bounds__(128) void node_post_kernel(
    const float* __restrict__ nacc, const float* __restrict__ node_attr,
    const float* __restrict__ w_lin2_0, const float* __restrict__ w_lin2_1,
    const float* __restrict__ w_alpha, float* __restrict__ out)
{
    const int n0 = blockIdx.x * 8, t = threadIdx.x;
    __shared__ __align__(16) float sn[8 * 256];
    __shared__ float salpha[8];
    const float4* src = (const float4*)(nacc + (size_t)n0 * 256);
    #pragma unroll
    for (int i = 0; i < 4; ++i) ((float4*)sn)[t + i * 128] = src[t + i * 128];
    __syncthreads();

    if (t < 64) {
        const float wa = w_alpha[t];
        #pragma unroll
        for (int k = 0; k < 8; ++k) {
            const float r = wave_reduce_dpp(sn[k * 256 + t] * wa);
            if (t == 0) salpha[k] = r;
        }
    }
    __syncthreads();

    float wcol[64];
    int m = 0;
    if (t < 32) {
        #pragma unroll
        for (int u = 0; u < 64; ++u) wcol[u] = w_lin2_0[u * 32 + t];
    } else {
        const int j = t - 32; const int w = j / 3; m = j % 3;
        #pragma unroll
        for (int u = 0; u < 64; ++u) wcol[u] = w_lin2_1[u * 32 + w];
    }
    #pragma unroll
    for (int k = 0; k < 8; ++k) {
        const float* s = sn + k * 256;
        float acc = 0.f;
        if (t < 32) {
            #pragma unroll
            for (int u = 0; u < 64; ++u) acc += s[u] * wcol[u];
        } else {
            #pragma unroll
            for (int u = 0; u < 64; ++u) acc += s[64 + u * 3 + m] * wcol[u];
        }
        const float a  = node_attr[n0 + k];
        const float sc = a * S_MID * INV_NN;
        const size_t o = (size_t)(n0 + k) * 128 + t;
        out[o] = out[o] + (salpha[k] * sc) * (acc * sc);
    }
}

extern "C" void kernel_launch(void* const* d_in, const int* in_sizes, int n_in,
                              void* d_out, int out_size, void* d_ws, size_t ws_size,
                              hipStream_t stream)
{
    const float* node_input   = (const float*)d_in[0];
    const float* node_attr    = (const float*)d_in[1];
    const int*   edge_src     = (const int*)d_in[2];
    const int*   edge_dst     = (const int*)d_in[3];
    const float* edge_attr    = (const float*)d_in[4];
    const float* edge_scalars = (const float*)d_in[5];
    const float* w_sc0        = (const float*)d_in[6];
    const float* w_sc1        = (const float*)d_in[7];
    const float* w_lin1_0     = (const float*)d_in[8];
    const float* w_lin1_1     = (const float*)d_in[9];
    const float* fc_w1        = (const float*)d_in[10];
    const float* fc_w2        = (const float*)d_in[11];
    const float* w_lin2_0     = (const float*)d_in[12];
    const float* w_lin2_1     = (const float*)d_in[13];
    const float* w_alpha      = (const float*)d_in[14];
    const float* w_se0a       = (const float*)d_in[15];
    const float* w_se0b       = (const float*)d_in[16];
    const float* w_se1a       = (const float*)d_in[17];
    const float* w_se1b       = (const float*)d_in[18];

    float* out      = (float*)d_out;
    float* edge_out = out + (size_t)N_NODES * 128;

    float* ws_f   = (float*)d_ws;                          // N*128 f
    float* nacc   = ws_f + (size_t)N_NODES * 128;          // N*256 f
    int*   counts = (int*)(nacc + (size_t)N_NODES * 256);  // N
    int*   cursor = counts + N_NODES;                      // N
    int*   sid    = cursor + N_NODES;                      // E
    int*   bsum   = sid + E_EDGES;                         // 64

    hipMemsetAsync(nacc, 0,
        ((size_t)N_NODES * 256 + N_NODES) * sizeof(float), stream);  // nacc+counts

    pre_hist_kernel<<<NPRE_BLOCKS + NHIST_BLOCKS, 256, 0, stream>>>(
        node_input, node_attr, w_sc0, w_sc1, w_lin1_0, w_lin1_1, out, ws_f,
        edge_dst, counts);

    scan_block_kernel<<<49, 1024, 0, stream>>>(counts, cursor, bsum);
    scan_fixup_kernel<<<49, 1024, 0, stream>>>(cursor, bsum);
    scatter_kernel<<<(E_EDGES + 255) / 256, 256, 0, stream>>>(edge_dst, cursor, sid);

    edge_kernel<<<E_EDGES / 64, 256, 0, stream>>>(
        ws_f, edge_src, edge_dst, edge_attr, edge_scalars, fc_w1, fc_w2,
        w_se0a, w_se0b, w_se1a, w_se1b, sid, nacc, edge_out);

    node_post_kernel<<<N_NODES / 8, 128, 0, stream>>>(
        nacc, node_attr, w_lin2_0, w_lin2_1, w_alpha, out);
}